// Round 14
// baseline (84.199 us; speedup 1.0000x reference)
//
#include <hip/hip_runtime.h>

typedef unsigned short u16;
typedef __attribute__((ext_vector_type(8))) short short8;
typedef __attribute__((ext_vector_type(4))) float f32x4;

#define SEQ 3072
#define HID 1024
#define HEADS 16
#define HDIM 64
#define SEGLEN 380
#define SEGSTR 381
#define NSEG 8
#define LTOT 3047
#define VPAD 384  // padded per-segment stride in vT (16B-aligned bases)

static __device__ __forceinline__ u16 f2bf(float f) {
  unsigned u = __builtin_bit_cast(unsigned, f);
  u += 0x7fffu + ((u >> 16) & 1u);
  return (u16)(u >> 16);
}
static __device__ __forceinline__ float bf2f(u16 h) {
  unsigned u = ((unsigned)h) << 16;
  return __builtin_bit_cast(float, u);
}

static __device__ __forceinline__ void load_lds16(const void* g, void* l) {
  __builtin_amdgcn_global_load_lds((const __attribute__((address_space(1))) void*)g,
                                   (__attribute__((address_space(3))) void*)l, 16, 0, 0);
}

#define BAR() __builtin_amdgcn_s_barrier()
#define FENCE() asm volatile("" ::: "memory")
#define VM(N) asm volatile("s_waitcnt vmcnt(" #N ")" ::: "memory")

// ---------------- merged f32 -> bf16 conversion (x4 vectorized) ----------------
__global__ void cvt_all_kernel(const float* __restrict__ x, const float* __restrict__ wq,
                               const float* __restrict__ wk, const float* __restrict__ wv,
                               const float* __restrict__ wo, u16* __restrict__ out) {
  const int i = blockIdx.x * 256 + threadIdx.x;  // float4 index, total 1835008
  const float* s;
  int base;
  if (i < 786432)       { s = x;  base = 0; }
  else if (i < 1048576) { s = wq; base = 786432; }
  else if (i < 1310720) { s = wk; base = 1048576; }
  else if (i < 1572864) { s = wv; base = 1310720; }
  else                  { s = wo; base = 1572864; }
  float4 v = reinterpret_cast<const float4*>(s)[i - base];
  unsigned long long o = (unsigned long long)f2bf(v.x) |
                         ((unsigned long long)f2bf(v.y) << 16) |
                         ((unsigned long long)f2bf(v.z) << 32) |
                         ((unsigned long long)f2bf(v.w) << 48);
  reinterpret_cast<unsigned long long*>(out)[i] = o;
}

// ====== QKV GEMM: 128x128 tile, producer/consumer waves, BK=32, 3 buffers ======
// 576 threads = 9 waves: wave 8 stages (global_load_lds), waves 0-7 compute.
// LDS row = 32 shorts (64B); physical chunk = logical ^ ((row>>1)&3), both sides.
// Producer stages one matrix = 8 wave-instrs (512 chunks of 16B), A+B = 16/tile.
static __device__ __forceinline__ void pstage_mat(
    const u16* __restrict__ src, u16* dst, int base, int k0, int lane) {
#pragma unroll
  for (int i = 0; i < 8; ++i) {
    const int ci = i * 64 + lane;
    const int row = ci >> 2;
    const int j = (ci & 3) ^ ((row >> 1) & 3);  // pre-swizzled source chunk
    load_lds16(src + (size_t)(base + row) * HID + k0 + j * 8, dst + i * 512);
  }
}

// consumer wave w: rows wr=(w>>2)*64 (4 m-frags); cols cb0 and cb0+32
static __device__ __forceinline__ void compute_qkv(
    const u16* As, const u16* Bs, int wr, int cb0, int lc, int lh, f32x4 (*acc)[2]) {
  short8 af[4], bfv[2];
#pragma unroll
  for (int m = 0; m < 4; ++m) {
    const int row = wr + m * 16 + lc;
    af[m] = *reinterpret_cast<const short8*>(As + row * 32 + (lh ^ ((row >> 1) & 3)) * 8);
  }
#pragma unroll
  for (int n = 0; n < 2; ++n) {
    const int row = cb0 + n * 32 + lc;
    bfv[n] = *reinterpret_cast<const short8*>(Bs + row * 32 + (lh ^ ((row >> 1) & 3)) * 8);
  }
  __builtin_amdgcn_s_setprio(1);
#pragma unroll
  for (int m = 0; m < 4; ++m)
#pragma unroll
    for (int n = 0; n < 2; ++n)
      acc[m][n] = __builtin_amdgcn_mfma_f32_16x16x32_bf16(af[m], bfv[n], acc[m][n], 0, 0, 0);
  __builtin_amdgcn_s_setprio(0);
}

// grid: (SEQ/128, 24); blockIdx.y: /8 -> {q,k,v}, &7 -> 128-col tile
__global__ __launch_bounds__(576) void qkv_gemm_kernel(
    const u16* __restrict__ xb,
    const u16* __restrict__ wqb, const u16* __restrict__ wkb, const u16* __restrict__ wvb,
    const float* __restrict__ bq, const float* __restrict__ bk, const float* __restrict__ bv,
    u16* __restrict__ qb, u16* __restrict__ kbuf, u16* __restrict__ vT) {
  __shared__ u16 As[3][128 * 32];
  __shared__ u16 Bs[3][128 * 32];
  const int which = blockIdx.y >> 3;
  const u16* Bw = (which == 0) ? wqb : (which == 1) ? wkb : wvb;
  const float* bias = (which == 0) ? bq : (which == 1) ? bk : bv;
  const int rowBase = blockIdx.x * 128;
  const int colBase = (blockIdx.y & 7) * 128;
  const int tid = threadIdx.x;
  const int w = tid >> 6, l = tid & 63, lc = l & 15, lh = l >> 4;

  if (w == 8) {
    // ---------------- producer wave ----------------
    const int lane = l;
#define PSTG(BUF, T)                                        \
  pstage_mat(xb, &As[BUF][0], rowBase, (T) * 32, lane);     \
  pstage_mat(Bw, &Bs[BUF][0], colBase, (T) * 32, lane);
    PSTG(0, 0);
    PSTG(1, 1);
    VM(16); BAR(); FENCE();  // B0: tile 0 landed
#pragma unroll 1
    for (int t = 0; t < 30; t += 3) {
      PSTG(2, t + 2); VM(16); BAR(); FENCE();  // tile t+1 landed
      PSTG(0, t + 3); VM(16); BAR(); FENCE();  // tile t+2 landed
      PSTG(1, t + 4); VM(16); BAR(); FENCE();  // tile t+3 landed
    }
    VM(0); BAR(); FENCE();  // B31: tile 31 landed
#undef PSTG
    return;
  }

  // ---------------- consumer waves (0..7) ----------------
  const int wr = (w >> 2) * 64;
  const int c2 = w & 3;
  const int cb0 = (c2 >> 1) * 64 + (c2 & 1) * 16;

  f32x4 acc[4][2];
  f32x4 z4 = {0.f, 0.f, 0.f, 0.f};
#pragma unroll
  for (int m = 0; m < 4; ++m) { acc[m][0] = z4; acc[m][1] = z4; }

  BAR(); FENCE();  // B0
#pragma unroll 1
  for (int t = 0; t < 30; t += 3) {
    compute_qkv(As[0], Bs[0], wr, cb0, lc, lh, acc);
    BAR(); FENCE();
    compute_qkv(As[1], Bs[1], wr, cb0, lc, lh, acc);
    BAR(); FENCE();
    compute_qkv(As[2], Bs[2], wr, cb0, lc, lh, acc);
    BAR(); FENCE();
  }
  compute_qkv(As[0], Bs[0], wr, cb0, lc, lh, acc);  // tile 30
  BAR(); FENCE();                                    // B31
  compute_qkv(As[1], Bs[1], wr, cb0, lc, lh, acc);  // tile 31

  // epilogue: thread holds cols (col0, col0+32) -> RoPE pair is local
  const int f = (c2 & 1) * 16 + lc;  // [0,32)
  const int col0 = colBase + (c2 >> 1) * 64 + f;
  if (which < 2) {
    u16* outp = which ? kbuf : qb;
    const float bv0 = bias[col0];
    const float bv1 = bias[col0 + 32];
    const float invf = exp2f(-(float)f * 0.10381025296523007f);  // 10^(-f/32)
#pragma unroll
    for (int m = 0; m < 4; ++m) {
      const int row0 = rowBase + wr + m * 16 + lh * 4;
#pragma unroll
      for (int r = 0; r < 4; ++r) {
        const int row = row0 + r;
        const int rr = row % SEGSTR;
        const float pos = (float)((rr < SEGLEN) ? rr : 0);
        float sn, cs;
        sincosf(pos * invf, &sn, &cs);
        const float t1 = acc[m][0][r] + bv0;
        const float t2 = acc[m][1][r] + bv1;
        const size_t base = (size_t)row * HID + col0;
        outp[base] = f2bf(t1 * cs - t2 * sn);
        outp[base + 32] = f2bf(t1 * sn + t2 * cs);
      }
    }
  } else {
#pragma unroll
    for (int n = 0; n < 2; ++n) {
      const int col = col0 + n * 32;
      const float bvl = bias[col];
#pragma unroll
      for (int m = 0; m < 4; ++m) {
        const int row0 = rowBase + wr + m * 16 + lh * 4;
#pragma unroll
        for (int r = 0; r < 4; ++r) {
          const float v = acc[m][n][r] + bvl;
          const int row = row0 + r;
          const int sg = row / SEGSTR;
          const int j = row - sg * SEGSTR;
          if (sg < NSEG)
            vT[(size_t)col * (NSEG * VPAD) + sg * VPAD + j] = f2bf(v);
        }
      }
    }
  }
}

// ================= OUT GEMM: 128x64 tile, 512 threads (8 waves), BK=64 =========
// LDS row = 64 shorts (128B); physical chunk = logical ^ (row&7), both sides.
static __device__ __forceinline__ void stage_out(
    const u16* __restrict__ A, const u16* __restrict__ Bw,
    u16* As, u16* Bs, int rowBase, int colBase, int k0) {
  const int tid = threadIdx.x;
  const int w = tid >> 6;
#pragma unroll
  for (int c = 0; c < 2; ++c) {
    const int li = c * 512 + tid;
    const int row = li >> 3;
    const int j = (li & 7) ^ (row & 7);
    load_lds16(A + (size_t)(rowBase + row) * HID + k0 + j * 8,
               As + (c * 512 + w * 64) * 8);
  }
  {
    const int row = tid >> 3;
    const int j = (tid & 7) ^ (row & 7);
    load_lds16(Bw + (size_t)(colBase + row) * HID + k0 + j * 8, Bs + (w * 64) * 8);
  }
}

// wave w: rows wrO=(w>>1)*32 (2 m-frags), cols wcO=(w&1)*32 (2 n-frags), 2 k-subs
static __device__ __forceinline__ void compute_out(
    const u16* As, const u16* Bs, int wrO, int wcO, int lc, int lh, f32x4 (*acc)[2]) {
  short8 af[2][2], bfv[2][2];
#pragma unroll
  for (int m = 0; m < 2; ++m) {
    const int row = wrO + m * 16 + lc;
#pragma unroll
    for (int ks = 0; ks < 2; ++ks)
      af[m][ks] = *reinterpret_cast<const short8*>(
          As + row * 64 + (((ks * 4 + lh) ^ (row & 7))) * 8);
  }
#pragma unroll
  for (int n = 0; n < 2; ++n) {
    const int row = wcO + n * 16 + lc;
#pragma unroll
    for (int ks = 0; ks < 2; ++ks)
      bfv[n][ks] = *reinterpret_cast<const short8*>(
          Bs + row * 64 + (((ks * 4 + lh) ^ (row & 7))) * 8);
  }
  __builtin_amdgcn_s_setprio(1);
#pragma unroll
  for (int ks = 0; ks < 2; ++ks)
#pragma unroll
    for (int m = 0; m < 2; ++m)
#pragma unroll
      for (int n = 0; n < 2; ++n)
        acc[m][n] = __builtin_amdgcn_mfma_f32_16x16x32_bf16(af[m][ks], bfv[n][ks], acc[m][n], 0, 0, 0);
  __builtin_amdgcn_s_setprio(0);
}

// grid: (SEQ/128, HID/64), 512 threads
__global__ __launch_bounds__(512) void out_gemm_kernel(
    const u16* __restrict__ aob, const u16* __restrict__ wob,
    const float* __restrict__ bo, float* __restrict__ out) {
  __shared__ u16 As[3][128 * 64];
  __shared__ u16 Bs[3][64 * 64];
  const int rowBase = blockIdx.x * 128;
  const int colBase = blockIdx.y * 64;
  const int tid = threadIdx.x;
  const int w = tid >> 6, l = tid & 63, lc = l & 15, lh = l >> 4;
  const int wrO = (w >> 1) * 32, wcO = (w & 1) * 32;
  f32x4 acc[2][2];
  f32x4 z4 = {0.f, 0.f, 0.f, 0.f};
#pragma unroll
  for (int m = 0; m < 2; ++m) { acc[m][0] = z4; acc[m][1] = z4; }

  stage_out(aob, wob, As[0], Bs[0], rowBase, colBase, 0);
  stage_out(aob, wob, As[1], Bs[1], rowBase, colBase, 64);
#pragma unroll 1
  for (int t = 0; t < 12; t += 3) {
    stage_out(aob, wob, As[2], Bs[2], rowBase, colBase, (t + 2) * 64);
    VM(6); BAR();
    compute_out(As[0], Bs[0], wrO, wcO, lc, lh, acc);
    BAR();
    stage_out(aob, wob, As[0], Bs[0], rowBase, colBase, (t + 3) * 64);
    VM(6); BAR();
    compute_out(As[1], Bs[1], wrO, wcO, lc, lh, acc);
    BAR();
    stage_out(aob, wob, As[1], Bs[1], rowBase, colBase, (t + 4) * 64);
    VM(6); BAR();
    compute_out(As[2], Bs[2], wrO, wcO, lc, lh, acc);
    BAR();
  }
  // computed 0..11, staged 0..13
  stage_out(aob, wob, As[2], Bs[2], rowBase, colBase, 14 * 64);
  VM(6); BAR();
  compute_out(As[0], Bs[0], wrO, wcO, lc, lh, acc);  // 12
  BAR();
  stage_out(aob, wob, As[0], Bs[0], rowBase, colBase, 15 * 64);
  VM(6); BAR();
  compute_out(As[1], Bs[1], wrO, wcO, lc, lh, acc);  // 13
  BAR();
  VM(3); BAR();
  compute_out(As[2], Bs[2], wrO, wcO, lc, lh, acc);  // 14
  BAR();
  VM(0); BAR();
  compute_out(As[0], Bs[0], wrO, wcO, lc, lh, acc);  // 15

#pragma unroll
  for (int n = 0; n < 2; ++n) {
    const int col = colBase + wcO + n * 16 + lc;
    const float bvl = bo[col];
#pragma unroll
    for (int m = 0; m < 2; ++m) {
      const int row0 = rowBase + wrO + m * 16 + lh * 4;
#pragma unroll
      for (int r = 0; r < 4; ++r)
        out[(size_t)(row0 + r) * HID + col] = acc[m][n][r] + bvl;
    }
  }
}

// ---------- block-diagonal flash attention (LDS-staged K/V, no-max softmax) -------
// Block = (qtile, seg, head) via XCD-chunked 1-D swizzle; 4 waves x 16 q-rows.
// K/V staged to LDS once per block (global_load_lds), triple-buffered, depth-2
// counted vmcnt. Fixup (separator/pad rows) fused into qt==5 blocks.
__global__ __launch_bounds__(256) void attn_kernel(
    const u16* __restrict__ qb, const u16* __restrict__ kb,
    const u16* __restrict__ vT, u16* __restrict__ ao) {
  __shared__ u16 Ks[3][32 * 64];
  __shared__ u16 Vs[3][64 * 32];
  __shared__ u16 P_lds[4][16 * 32];
  const int tid = threadIdx.x;
  const int w = tid >> 6, l = tid & 63, lc = l & 15, lh = l >> 4;
  // XCD-chunked swizzle: 768 blocks = 8 XCDs x 96; the 6 qtiles of a (seg,h)
  // group stay on one XCD -> K/V L2 reuse.
  const int W = (blockIdx.x & 7) * 96 + (blockIdx.x >> 3);
  const int qt = W % 6;
  const int seg = (W / 6) & 7;
  const int h = W / 48;
  const int segbase = seg * SEGSTR;
  const int rloc = qt * 64 + w * 16;

  const u16* qrow = qb + (size_t)(segbase + rloc + lc) * HID + h * HDIM + lh * 8;
  const short8 qf0 = *reinterpret_cast<const short8*>(qrow);
  const short8 qf1 = *reinterpret_cast<const short8*>(qrow + 32);

  const size_t vstride = (size_t)NSEG * VPAD;
  const u16* kseg = kb + (size_t)segbase * HID + h * HDIM;
  const u16* vseg = vT + (size_t)h * HDIM * vstride + seg * VPAD;

  // staging lane roles
  const int krow = tid >> 3;                       // 32 k-rows, 8 chunks of 16B
  const int kj = (tid & 7) ^ (krow & 7);           // pre-swizzled source chunk
  const int vd = tid >> 2;                         // 64 d-rows, 4 chunks of 16B
  const int vj = (tid & 3) ^ ((vd >> 2) & 3);

  f32x4 z4 = {0.f, 0.f, 0.f, 0.f};
  f32x4 accO[4] = {z4, z4, z4, z4};
  float psum[4] = {0.f, 0.f, 0.f, 0.f};

  // P_lds (per-wave [16 q][32 k]) swizzled offsets
  u16* pl = &P_lds[w][0];
  int wo0[4], wo1[4];
#pragma unroll
  for (int r = 0; r < 4; ++r) {
    const int prow = lh * 4 + r;
    const int sw = (prow >> 1) & 3;
    wo0[r] = prow * 32 + ((lc >> 3) ^ sw) * 8 + (lc & 7);
    wo1[r] = prow * 32 + ((2 + (lc >> 3)) ^ sw) * 8 + (lc & 7);
  }
  const int prd_off = lc * 32 + (lh ^ ((lc >> 1) & 3)) * 8;

#define STAGE(B, T)                                                                 \
  load_lds16(kseg + (size_t)((T) * 32 + krow) * HID + kj * 8, &Ks[B][0] + w * 512); \
  load_lds16(vseg + (size_t)vd * vstride + (T) * 32 + vj * 8, &Vs[B][0] + w * 512);

#define STEP(B, MASKED)                                                               \
  {                                                                                   \
    const u16* KB = &Ks[B][0];                                                        \
    const u16* VB = &Vs[B][0];                                                        \
    const int ks0 = (lh ^ (lc & 7)) * 8;                                              \
    const int ks1 = ((lh + 4) ^ (lc & 7)) * 8;                                        \
    const short8 k00 = *reinterpret_cast<const short8*>(KB + lc * 64 + ks0);          \
    const short8 k01 = *reinterpret_cast<const short8*>(KB + lc * 64 + ks1);          \
    const short8 k10 = *reinterpret_cast<const short8*>(KB + (16 + lc) * 64 + ks0);   \
    const short8 k11 = *reinterpret_cast<const short8*>(KB + (16 + lc) * 64 + ks1);   \
    f32x4 s0 = z4, s1 = z4;                                                           \
    __builtin_amdgcn_s_setprio(1);                                                    \
    s0 = __builtin_amdgcn_mfma_f32_16x16x32_bf16(qf0, k00, s0, 0, 0, 0);              \
    s0 = __builtin_amdgcn_mfma_f32_16x16x32_bf16(qf1, k01, s0, 0, 0, 0);              \
    s1 = __builtin_amdgcn_mfma_f32_16x16x32_bf16(qf0, k10, s1, 0, 0, 0);              \
    s1 = __builtin_amdgcn_mfma_f32_16x16x32_bf16(qf1, k11, s1, 0, 0, 0);              \
    __builtin_amdgcn_s_setprio(0);                                                    \
    float p0[4], p1[4];                                                               \
    _Pragma("unroll") for (int r = 0; r < 4; ++r) {                                   \
      p0[r] = (!(MASKED) || lc < 28) ? __expf(s0[r] * 0.125f) : 0.f;                  \
      p1[r] = (!(MASKED) || lc < 12) ? __expf(s1[r] * 0.125f) : 0.f;                  \
      psum[r] += p0[r] + p1[r];                                                       \
    }                                                                                 \
    _Pragma("unroll") for (int r = 0; r < 4; ++r) {                                   \
      pl[wo0[r]] = f2bf(p0[r]);                                                       \
      pl[wo1[r]] = f2bf(p1[r]);                                                       \
    }                                                                                 \
    const short8 pf = *reinterpret_cast<const short8*>(pl + prd_off);                 \
    const int vsw = (lh ^ (lc >> 2)) * 8;                                             \
    const short8 v0 = *reinterpret_cast<const short8*>(VB + lc * 32 + vsw);           \
    const short8 v1 = *reinterpret_cast<const short8*>(VB + (16 + lc) * 32 + vsw);    \
    const short8 v2 = *reinterpret_cast<const short8*>(VB + (32 + lc) * 32 + vsw);    \
    const short8 v3 = *reinterpret_cast<const short8*>(VB + (48 + lc) * 32 + vsw);    \
    __builtin_amdgcn_s_setprio(1);                                                    \
    accO[0] = __builtin_amdgcn_mfma_f32_16x16x32_bf16(pf, v0, accO[0], 0, 0, 0);      \
    accO[1] = __builtin_amdgcn_mfma_f32_16x16x32_bf16(pf, v1, accO[1], 0, 0, 0);      \
    accO[2] = __builtin_amdgcn_mfma_f32_16x16x32_bf16(pf, v2, accO[2], 0, 0, 0);      \
    accO[3] = __builtin_amdgcn_mfma_f32_16x16x32_bf16(pf, v3, accO[3], 0, 0, 0);      \
    __builtin_amdgcn_s_setprio(0);                                                    \
  }

  STAGE(0, 0);
  STAGE(1, 1);
#pragma unroll 1
  for (int t = 0; t < 9; t += 3) {
    STAGE(2, t + 2);
    VM(4); BAR();
    STEP(0, false);
    BAR();
    STAGE(0, t + 3);
    VM(4); BAR();
    STEP(1, false);
    BAR();
    STAGE(1, t + 4);
    VM(4); BAR();
    STEP(2, false);
    BAR();
  }
  // steps 0..8 done; staged 9(b0), 10(b1). Step 9 + stage 11(b2):
  STAGE(2, 11);
  VM(4); BAR();
  STEP(0, false);  // step 9
  BAR();
  VM(2); BAR();
  STEP(1, false);  // step 10
  BAR();
  VM(0); BAR();
  STEP(2, true);   // step 11: k rows 352..383, mask k >= 380
#undef STEP
#undef STAGE

  float inv[4];
#pragma unroll
  for (int r = 0; r < 4; ++r) {
    float s = psum[r];
    s += __shfl_xor(s, 1);
    s += __shfl_xor(s, 2);
    s += __shfl_xor(s, 4);
    s += __shfl_xor(s, 8);
    inv[r] = 1.0f / s;
  }
#pragma unroll
  for (int r = 0; r < 4; ++r) {
    const int lrow = rloc + lh * 4 + r;
    if (lrow < SEGLEN) {
      const size_t orow = (size_t)(segbase + lrow) * HID + h * HDIM;
#pragma unroll
      for (int n = 0; n < 4; ++n)
        ao[orow + n * 16 + lc] = f2bf(accO[n][r] * inv[r]);
    }
  }

  // fused fixup: qt==5 blocks also write separator / pad rows for (seg, h)
  if (qt == 5) {
    if (seg < NSEG - 1) {
      if (tid < HDIM)
        ao[(size_t)(segbase + SEGLEN) * HID + h * HDIM + tid] =
            vT[(size_t)(h * HDIM + tid) * vstride + seg * VPAD + SEGLEN];
    } else {
      // zero rows 3047..3071 in this head's 64 columns (25 rows x 64 cols)
#pragma unroll
      for (int k = 0; k < 7; ++k) {
        const int idx = k * 256 + tid;
        if (idx < 25 * HDIM) {
          const int rr = idx >> 6, cc = idx & 63;
          ao[(size_t)(LTOT + rr) * HID + h * HDIM + cc] = 0;
        }
      }
    }
  }
}

extern "C" void kernel_launch(void* const* d_in, const int* in_sizes, int n_in,
                              void* d_out, int out_size, void* d_ws, size_t ws_size,
                              hipStream_t stream) {
  const float* x  = (const float*)d_in[0];
  const float* wq = (const float*)d_in[1];
  const float* bq = (const float*)d_in[2];
  const float* wk = (const float*)d_in[3];
  const float* bk = (const float*)d_in[4];
  const float* wv = (const float*)d_in[5];
  const float* bv = (const float*)d_in[6];
  const float* wo = (const float*)d_in[7];
  const float* bo = (const float*)d_in[8];
  float* out = (float*)d_out;

  u16* ws = (u16*)d_ws;
  u16* xb   = ws;                    // SEQ*HID
  u16* wqb  = xb  + (size_t)SEQ * HID;
  u16* wkb  = wqb + (size_t)HID * HID;
  u16* wvb  = wkb + (size_t)HID * HID;
  u16* wob  = wvb + (size_t)HID * HID;
  u16* qb   = wob + (size_t)HID * HID;
  u16* kbuf = qb  + (size_t)SEQ * HID;
  u16* vT   = kbuf + (size_t)SEQ * HID;  // [HID][NSEG*VPAD]
  u16* aob  = vT  + (size_t)HID * (NSEG * VPAD);

  cvt_all_kernel<<<7168, 256, 0, stream>>>(x, wq, wk, wv, wo, ws);

  qkv_gemm_kernel<<<dim3(SEQ / 128, 24), 576, 0, stream>>>(
      xb, wqb, wkb, wvb, bq, bk, bv, qb, kbuf, vT);

  attn_kernel<<<768, 256, 0, stream>>>(qb, kbuf, vT, aob);

  out_gemm_kernel<<<dim3(SEQ / 128, HID / 64), 512, 0, stream>>>(aob, wob, bo, out);

  (void)in_sizes; (void)n_in; (void)out_size; (void)ws_size;
}

// Round 15
// 74.327 us; speedup vs baseline: 1.1328x; 1.1328x over previous
//
#include <hip/hip_runtime.h>

typedef unsigned short u16;
typedef __attribute__((ext_vector_type(8))) short short8;
typedef __attribute__((ext_vector_type(4))) float f32x4;

#define SEQ 3072
#define HID 1024
#define HEADS 16
#define HDIM 64
#define SEGLEN 380
#define SEGSTR 381
#define NSEG 8
#define LTOT 3047
#define VPAD 384  // padded per-segment stride in vT (16B-aligned bases)

static __device__ __forceinline__ u16 f2bf(float f) {
  unsigned u = __builtin_bit_cast(unsigned, f);
  u += 0x7fffu + ((u >> 16) & 1u);
  return (u16)(u >> 16);
}
static __device__ __forceinline__ float bf2f(u16 h) {
  unsigned u = ((unsigned)h) << 16;
  return __builtin_bit_cast(float, u);
}

static __device__ __forceinline__ void load_lds16(const void* g, void* l) {
  __builtin_amdgcn_global_load_lds((const __attribute__((address_space(1))) void*)g,
                                   (__attribute__((address_space(3))) void*)l, 16, 0, 0);
}

#define BAR() __builtin_amdgcn_s_barrier()
#define VM(N) asm volatile("s_waitcnt vmcnt(" #N ")" ::: "memory")

// ------- f32 -> bf16 conversion + tiling for qkv operands -------
// x -> xblk [24 Mtile][32 Ktile][128 row][32 k] with chunk swizzle baked in:
//   chunk position (row, cp) holds logical k-chunk cp ^ ((row>>1)&3).
// wq|wk|wv -> wblk [24 Ctile][32 Ktile][128][32] same scheme.
// wo -> linear (out_gemm unchanged). All dst = ws + d*8 (d = global chunk id).
__global__ void cvt_all_kernel(const float* __restrict__ x, const float* __restrict__ wq,
                               const float* __restrict__ wk, const float* __restrict__ wv,
                               const float* __restrict__ wo, u16* __restrict__ ws) {
  const int d = blockIdx.x * 256 + threadIdx.x;  // 16B-chunk index, total 917504
  const float* src;
  if (d < 393216) {  // x blocked
    const int tm = d >> 14, rem = d & 16383;
    const int tk = rem >> 9, rem2 = rem & 511;
    const int row = rem2 >> 2, cp = rem2 & 3;
    const int j = cp ^ ((row >> 1) & 3);
    src = x + ((size_t)(tm * 128 + row) * HID + tk * 32 + j * 8);
  } else if (d < 786432) {  // weights blocked
    const int dd = d - 393216;
    const int tc = dd >> 14, rem = dd & 16383;
    const int tk = rem >> 9, rem2 = rem & 511;
    const int row = rem2 >> 2, cp = rem2 & 3;
    const int j = cp ^ ((row >> 1) & 3);
    const int which = tc >> 3;
    const float* wsrc = (which == 0) ? wq : (which == 1) ? wk : wv;
    src = wsrc + ((size_t)((tc & 7) * 128 + row) * HID + tk * 32 + j * 8);
  } else {  // wo linear
    src = wo + (size_t)(d - 786432) * 8;
  }
  float4 a = *reinterpret_cast<const float4*>(src);
  float4 b = *reinterpret_cast<const float4*>(src + 4);
  unsigned long long o0 = (unsigned long long)f2bf(a.x) |
                          ((unsigned long long)f2bf(a.y) << 16) |
                          ((unsigned long long)f2bf(a.z) << 32) |
                          ((unsigned long long)f2bf(a.w) << 48);
  unsigned long long o1 = (unsigned long long)f2bf(b.x) |
                          ((unsigned long long)f2bf(b.y) << 16) |
                          ((unsigned long long)f2bf(b.z) << 32) |
                          ((unsigned long long)f2bf(b.w) << 48);
  unsigned long long* dst = reinterpret_cast<unsigned long long*>(ws + (size_t)d * 8);
  dst[0] = o0;
  dst[1] = o1;
}

// ===== QKV GEMM: 128x128 tile, 512 thr (8 waves), BK=32, blocked operands =====
// Each K-tile is a contiguous pre-swizzled 8KB block -> staging is fully linear.
static __device__ __forceinline__ void stage_qkv(
    const u16* __restrict__ Ablk, const u16* __restrict__ Bblk,
    u16* As, u16* Bs, int t) {
  const int tid = threadIdx.x;
  const int w = tid >> 6;
  load_lds16(Ablk + (size_t)t * 4096 + tid * 8, As + (w * 64) * 8);
  load_lds16(Bblk + (size_t)t * 4096 + tid * 8, Bs + (w * 64) * 8);
}

// wave w: rows wr=(w>>2)*64 (4 m-frags); cols cb0=(c2>>1)*64+(c2&1)*16 and cb0+32
static __device__ __forceinline__ void compute_qkv(
    const u16* As, const u16* Bs, int wr, int cb0, int lc, int lh, f32x4 (*acc)[2]) {
  short8 af[4], bfv[2];
#pragma unroll
  for (int m = 0; m < 4; ++m) {
    const int row = wr + m * 16 + lc;
    af[m] = *reinterpret_cast<const short8*>(As + row * 32 + (lh ^ ((row >> 1) & 3)) * 8);
  }
#pragma unroll
  for (int n = 0; n < 2; ++n) {
    const int row = cb0 + n * 32 + lc;
    bfv[n] = *reinterpret_cast<const short8*>(Bs + row * 32 + (lh ^ ((row >> 1) & 3)) * 8);
  }
  __builtin_amdgcn_s_setprio(1);
#pragma unroll
  for (int m = 0; m < 4; ++m)
#pragma unroll
    for (int n = 0; n < 2; ++n)
      acc[m][n] = __builtin_amdgcn_mfma_f32_16x16x32_bf16(af[m], bfv[n], acc[m][n], 0, 0, 0);
  __builtin_amdgcn_s_setprio(0);
}

// grid: (SEQ/128, 24); blockIdx.y: /8 -> {q,k,v}, &7 -> 128-col tile
__global__ __launch_bounds__(512) void qkv_gemm_kernel(
    const u16* __restrict__ xblk, const u16* __restrict__ wblk,
    const float* __restrict__ bq, const float* __restrict__ bk, const float* __restrict__ bv,
    u16* __restrict__ qb, u16* __restrict__ kbuf, u16* __restrict__ vT) {
  __shared__ u16 As[3][128 * 32];
  __shared__ u16 Bs[3][128 * 32];
  const int which = blockIdx.y >> 3;
  const float* bias = (which == 0) ? bq : (which == 1) ? bk : bv;
  const int rowBase = blockIdx.x * 128;
  const int colBase = (blockIdx.y & 7) * 128;
  const u16* Ablk = xblk + (size_t)blockIdx.x * 131072;  // 32 tiles * 4096
  const u16* Bblk = wblk + (size_t)blockIdx.y * 131072;
  const int tid = threadIdx.x;
  const int w = tid >> 6, l = tid & 63, lc = l & 15, lh = l >> 4;
  const int wr = (w >> 2) * 64;
  const int c2 = w & 3;
  const int cb0 = (c2 >> 1) * 64 + (c2 & 1) * 16;

  f32x4 acc[4][2];
  f32x4 z4 = {0.f, 0.f, 0.f, 0.f};
#pragma unroll
  for (int m = 0; m < 4; ++m) { acc[m][0] = z4; acc[m][1] = z4; }

  stage_qkv(Ablk, Bblk, As[0], Bs[0], 0);
  stage_qkv(Ablk, Bblk, As[1], Bs[1], 1);
#pragma unroll 1
  for (int t = 0; t < 30; t += 3) {
    stage_qkv(Ablk, Bblk, As[2], Bs[2], t + 2);
    VM(4); BAR();
    compute_qkv(As[0], Bs[0], wr, cb0, lc, lh, acc);
    BAR();
    stage_qkv(Ablk, Bblk, As[0], Bs[0], t + 3);
    VM(4); BAR();
    compute_qkv(As[1], Bs[1], wr, cb0, lc, lh, acc);
    BAR();
    stage_qkv(Ablk, Bblk, As[1], Bs[1], t + 4);
    VM(4); BAR();
    compute_qkv(As[2], Bs[2], wr, cb0, lc, lh, acc);
    BAR();
  }
  VM(2); BAR();
  compute_qkv(As[0], Bs[0], wr, cb0, lc, lh, acc);  // tile 30
  BAR();
  VM(0); BAR();
  compute_qkv(As[1], Bs[1], wr, cb0, lc, lh, acc);  // tile 31

  // epilogue: thread holds cols (col0, col0+32) -> RoPE pair is local
  const int f = (c2 & 1) * 16 + lc;  // [0,32)
  const int col0 = colBase + (c2 >> 1) * 64 + f;
  if (which < 2) {
    u16* outp = which ? kbuf : qb;
    const float bv0 = bias[col0];
    const float bv1 = bias[col0 + 32];
    const float invf = exp2f(-(float)f * 0.10381025296523007f);  // 10^(-f/32)
#pragma unroll
    for (int m = 0; m < 4; ++m) {
      const int row0 = rowBase + wr + m * 16 + lh * 4;
#pragma unroll
      for (int r = 0; r < 4; ++r) {
        const int row = row0 + r;
        const int rr = row % SEGSTR;
        const float pos = (float)((rr < SEGLEN) ? rr : 0);
        float sn, cs;
        sincosf(pos * invf, &sn, &cs);
        const float t1 = acc[m][0][r] + bv0;
        const float t2 = acc[m][1][r] + bv1;
        const size_t base = (size_t)row * HID + col0;
        outp[base] = f2bf(t1 * cs - t2 * sn);
        outp[base + 32] = f2bf(t1 * sn + t2 * cs);
      }
    }
  } else {
#pragma unroll
    for (int n = 0; n < 2; ++n) {
      const int col = col0 + n * 32;
      const float bvl = bias[col];
#pragma unroll
      for (int m = 0; m < 4; ++m) {
        const int row0 = rowBase + wr + m * 16 + lh * 4;
#pragma unroll
        for (int r = 0; r < 4; ++r) {
          const float v = acc[m][n][r] + bvl;
          const int row = row0 + r;
          const int sg = row / SEGSTR;
          const int j = row - sg * SEGSTR;
          if (sg < NSEG)
            vT[(size_t)col * (NSEG * VPAD) + sg * VPAD + j] = f2bf(v);
        }
      }
    }
  }
}

// ================= OUT GEMM: 128x64 tile, 512 threads (8 waves), BK=64 =========
// LDS row = 64 shorts (128B); physical chunk = logical ^ (row&7), both sides.
static __device__ __forceinline__ void stage_out(
    const u16* __restrict__ A, const u16* __restrict__ Bw,
    u16* As, u16* Bs, int rowBase, int colBase, int k0) {
  const int tid = threadIdx.x;
  const int w = tid >> 6;
#pragma unroll
  for (int c = 0; c < 2; ++c) {
    const int li = c * 512 + tid;
    const int row = li >> 3;
    const int j = (li & 7) ^ (row & 7);
    load_lds16(A + (size_t)(rowBase + row) * HID + k0 + j * 8,
               As + (c * 512 + w * 64) * 8);
  }
  {
    const int row = tid >> 3;
    const int j = (tid & 7) ^ (row & 7);
    load_lds16(Bw + (size_t)(colBase + row) * HID + k0 + j * 8, Bs + (w * 64) * 8);
  }
}

// wave w: rows wrO=(w>>1)*32 (2 m-frags), cols wcO=(w&1)*32 (2 n-frags), 2 k-subs
static __device__ __forceinline__ void compute_out(
    const u16* As, const u16* Bs, int wrO, int wcO, int lc, int lh, f32x4 (*acc)[2]) {
  short8 af[2][2], bfv[2][2];
#pragma unroll
  for (int m = 0; m < 2; ++m) {
    const int row = wrO + m * 16 + lc;
#pragma unroll
    for (int ks = 0; ks < 2; ++ks)
      af[m][ks] = *reinterpret_cast<const short8*>(
          As + row * 64 + (((ks * 4 + lh) ^ (row & 7))) * 8);
  }
#pragma unroll
  for (int n = 0; n < 2; ++n) {
    const int row = wcO + n * 16 + lc;
#pragma unroll
    for (int ks = 0; ks < 2; ++ks)
      bfv[n][ks] = *reinterpret_cast<const short8*>(
          Bs + row * 64 + (((ks * 4 + lh) ^ (row & 7))) * 8);
  }
  __builtin_amdgcn_s_setprio(1);
#pragma unroll
  for (int ks = 0; ks < 2; ++ks)
#pragma unroll
    for (int m = 0; m < 2; ++m)
#pragma unroll
      for (int n = 0; n < 2; ++n)
        acc[m][n] = __builtin_amdgcn_mfma_f32_16x16x32_bf16(af[m][ks], bfv[n][ks], acc[m][n], 0, 0, 0);
  __builtin_amdgcn_s_setprio(0);
}

// grid: (SEQ/128, HID/64), 512 threads
__global__ __launch_bounds__(512) void out_gemm_kernel(
    const u16* __restrict__ aob, const u16* __restrict__ wob,
    const float* __restrict__ bo, float* __restrict__ out) {
  __shared__ u16 As[3][128 * 64];
  __shared__ u16 Bs[3][64 * 64];
  const int rowBase = blockIdx.x * 128;
  const int colBase = blockIdx.y * 64;
  const int tid = threadIdx.x;
  const int w = tid >> 6, l = tid & 63, lc = l & 15, lh = l >> 4;
  const int wrO = (w >> 1) * 32, wcO = (w & 1) * 32;
  f32x4 acc[2][2];
  f32x4 z4 = {0.f, 0.f, 0.f, 0.f};
#pragma unroll
  for (int m = 0; m < 2; ++m) { acc[m][0] = z4; acc[m][1] = z4; }

  stage_out(aob, wob, As[0], Bs[0], rowBase, colBase, 0);
  stage_out(aob, wob, As[1], Bs[1], rowBase, colBase, 64);
#pragma unroll 1
  for (int t = 0; t < 12; t += 3) {
    stage_out(aob, wob, As[2], Bs[2], rowBase, colBase, (t + 2) * 64);
    VM(6); BAR();
    compute_out(As[0], Bs[0], wrO, wcO, lc, lh, acc);
    BAR();
    stage_out(aob, wob, As[0], Bs[0], rowBase, colBase, (t + 3) * 64);
    VM(6); BAR();
    compute_out(As[1], Bs[1], wrO, wcO, lc, lh, acc);
    BAR();
    stage_out(aob, wob, As[1], Bs[1], rowBase, colBase, (t + 4) * 64);
    VM(6); BAR();
    compute_out(As[2], Bs[2], wrO, wcO, lc, lh, acc);
    BAR();
  }
  // computed 0..11, staged 0..13
  stage_out(aob, wob, As[2], Bs[2], rowBase, colBase, 14 * 64);
  VM(6); BAR();
  compute_out(As[0], Bs[0], wrO, wcO, lc, lh, acc);  // 12
  BAR();
  stage_out(aob, wob, As[0], Bs[0], rowBase, colBase, 15 * 64);
  VM(6); BAR();
  compute_out(As[1], Bs[1], wrO, wcO, lc, lh, acc);  // 13
  BAR();
  VM(3); BAR();
  compute_out(As[2], Bs[2], wrO, wcO, lc, lh, acc);  // 14
  BAR();
  VM(0); BAR();
  compute_out(As[0], Bs[0], wrO, wcO, lc, lh, acc);  // 15

#pragma unroll
  for (int n = 0; n < 2; ++n) {
    const int col = colBase + wcO + n * 16 + lc;
    const float bvl = bo[col];
#pragma unroll
    for (int m = 0; m < 2; ++m) {
      const int row0 = rowBase + wrO + m * 16 + lh * 4;
#pragma unroll
      for (int r = 0; r < 4; ++r)
        out[(size_t)(row0 + r) * HID + col] = acc[m][n][r] + bvl;
    }
  }
}

// ---------- block-diagonal flash attention (LDS-staged K/V, no-max softmax) -------
// Block = (qtile, seg, head) via XCD-chunked 1-D swizzle; 4 waves x 16 q-rows.
// K/V staged to LDS once per block (global_load_lds), triple-buffered, depth-2
// counted vmcnt. Fixup (separator/pad rows) fused into qt==5 blocks.
__global__ __launch_bounds__(256) void attn_kernel(
    const u16* __restrict__ qb, const u16* __restrict__ kb,
    const u16* __restrict__ vT, u16* __restrict__ ao) {
  __shared__ u16 Ks[3][32 * 64];
  __shared__ u16 Vs[3][64 * 32];
  __shared__ u16 P_lds[4][16 * 32];
  const int tid = threadIdx.x;
  const int w = tid >> 6, l = tid & 63, lc = l & 15, lh = l >> 4;
  // XCD-chunked swizzle: 768 blocks = 8 XCDs x 96; the 6 qtiles of a (seg,h)
  // group stay on one XCD -> K/V L2 reuse.
  const int W = (blockIdx.x & 7) * 96 + (blockIdx.x >> 3);
  const int qt = W % 6;
  const int seg = (W / 6) & 7;
  const int h = W / 48;
  const int segbase = seg * SEGSTR;
  const int rloc = qt * 64 + w * 16;

  const u16* qrow = qb + (size_t)(segbase + rloc + lc) * HID + h * HDIM + lh * 8;
  const short8 qf0 = *reinterpret_cast<const short8*>(qrow);
  const short8 qf1 = *reinterpret_cast<const short8*>(qrow + 32);

  const size_t vstride = (size_t)NSEG * VPAD;
  const u16* kseg = kb + (size_t)segbase * HID + h * HDIM;
  const u16* vseg = vT + (size_t)h * HDIM * vstride + seg * VPAD;

  // staging lane roles
  const int krow = tid >> 3;                       // 32 k-rows, 8 chunks of 16B
  const int kj = (tid & 7) ^ (krow & 7);           // pre-swizzled source chunk
  const int vd = tid >> 2;                         // 64 d-rows, 4 chunks of 16B
  const int vj = (tid & 3) ^ ((vd >> 2) & 3);

  f32x4 z4 = {0.f, 0.f, 0.f, 0.f};
  f32x4 accO[4] = {z4, z4, z4, z4};
  float psum[4] = {0.f, 0.f, 0.f, 0.f};

  // P_lds (per-wave [16 q][32 k]) swizzled offsets
  u16* pl = &P_lds[w][0];
  int wo0[4], wo1[4];
#pragma unroll
  for (int r = 0; r < 4; ++r) {
    const int prow = lh * 4 + r;
    const int sw = (prow >> 1) & 3;
    wo0[r] = prow * 32 + ((lc >> 3) ^ sw) * 8 + (lc & 7);
    wo1[r] = prow * 32 + ((2 + (lc >> 3)) ^ sw) * 8 + (lc & 7);
  }
  const int prd_off = lc * 32 + (lh ^ ((lc >> 1) & 3)) * 8;

#define STAGE(B, T)                                                                 \
  load_lds16(kseg + (size_t)((T) * 32 + krow) * HID + kj * 8, &Ks[B][0] + w * 512); \
  load_lds16(vseg + (size_t)vd * vstride + (T) * 32 + vj * 8, &Vs[B][0] + w * 512);

#define STEP(B, MASKED)                                                               \
  {                                                                                   \
    const u16* KB = &Ks[B][0];                                                        \
    const u16* VB = &Vs[B][0];                                                        \
    const int ks0 = (lh ^ (lc & 7)) * 8;                                              \
    const int ks1 = ((lh + 4) ^ (lc & 7)) * 8;                                        \
    const short8 k00 = *reinterpret_cast<const short8*>(KB + lc * 64 + ks0);          \
    const short8 k01 = *reinterpret_cast<const short8*>(KB + lc * 64 + ks1);          \
    const short8 k10 = *reinterpret_cast<const short8*>(KB + (16 + lc) * 64 + ks0);   \
    const short8 k11 = *reinterpret_cast<const short8*>(KB + (16 + lc) * 64 + ks1);   \
    f32x4 s0 = z4, s1 = z4;                                                           \
    __builtin_amdgcn_s_setprio(1);                                                    \
    s0 = __builtin_amdgcn_mfma_f32_16x16x32_bf16(qf0, k00, s0, 0, 0, 0);              \
    s0 = __builtin_amdgcn_mfma_f32_16x16x32_bf16(qf1, k01, s0, 0, 0, 0);              \
    s1 = __builtin_amdgcn_mfma_f32_16x16x32_bf16(qf0, k10, s1, 0, 0, 0);              \
    s1 = __builtin_amdgcn_mfma_f32_16x16x32_bf16(qf1, k11, s1, 0, 0, 0);              \
    __builtin_amdgcn_s_setprio(0);                                                    \
    float p0[4], p1[4];                                                               \
    _Pragma("unroll") for (int r = 0; r < 4; ++r) {                                   \
      p0[r] = (!(MASKED) || lc < 28) ? __expf(s0[r] * 0.125f) : 0.f;                  \
      p1[r] = (!(MASKED) || lc < 12) ? __expf(s1[r] * 0.125f) : 0.f;                  \
      psum[r] += p0[r] + p1[r];                                                       \
    }                                                                                 \
    _Pragma("unroll") for (int r = 0; r < 4; ++r) {                                   \
      pl[wo0[r]] = f2bf(p0[r]);                                                       \
      pl[wo1[r]] = f2bf(p1[r]);                                                       \
    }                                                                                 \
    const short8 pf = *reinterpret_cast<const short8*>(pl + prd_off);                 \
    const int vsw = (lh ^ (lc >> 2)) * 8;                                             \
    const short8 v0 = *reinterpret_cast<const short8*>(VB + lc * 32 + vsw);           \
    const short8 v1 = *reinterpret_cast<const short8*>(VB + (16 + lc) * 32 + vsw);    \
    const short8 v2 = *reinterpret_cast<const short8*>(VB + (32 + lc) * 32 + vsw);    \
    const short8 v3 = *reinterpret_cast<const short8*>(VB + (48 + lc) * 32 + vsw);    \
    __builtin_amdgcn_s_setprio(1);                                                    \
    accO[0] = __builtin_amdgcn_mfma_f32_16x16x32_bf16(pf, v0, accO[0], 0, 0, 0);      \
    accO[1] = __builtin_amdgcn_mfma_f32_16x16x32_bf16(pf, v1, accO[1], 0, 0, 0);      \
    accO[2] = __builtin_amdgcn_mfma_f32_16x16x32_bf16(pf, v2, accO[2], 0, 0, 0);      \
    accO[3] = __builtin_amdgcn_mfma_f32_16x16x32_bf16(pf, v3, accO[3], 0, 0, 0);      \
    __builtin_amdgcn_s_setprio(0);                                                    \
  }

  STAGE(0, 0);
  STAGE(1, 1);
#pragma unroll 1
  for (int t = 0; t < 9; t += 3) {
    STAGE(2, t + 2);
    VM(4); BAR();
    STEP(0, false);
    BAR();
    STAGE(0, t + 3);
    VM(4); BAR();
    STEP(1, false);
    BAR();
    STAGE(1, t + 4);
    VM(4); BAR();
    STEP(2, false);
    BAR();
  }
  // steps 0..8 done; staged 9(b0), 10(b1). Step 9 + stage 11(b2):
  STAGE(2, 11);
  VM(4); BAR();
  STEP(0, false);  // step 9
  BAR();
  VM(2); BAR();
  STEP(1, false);  // step 10
  BAR();
  VM(0); BAR();
  STEP(2, true);   // step 11: k rows 352..383, mask k >= 380
#undef STEP
#undef STAGE

  float inv[4];
#pragma unroll
  for (int r = 0; r < 4; ++r) {
    float s = psum[r];
    s += __shfl_xor(s, 1);
    s += __shfl_xor(s, 2);
    s += __shfl_xor(s, 4);
    s += __shfl_xor(s, 8);
    inv[r] = 1.0f / s;
  }
#pragma unroll
  for (int r = 0; r < 4; ++r) {
    const int lrow = rloc + lh * 4 + r;
    if (lrow < SEGLEN) {
      const size_t orow = (size_t)(segbase + lrow) * HID + h * HDIM;
#pragma unroll
      for (int n = 0; n < 4; ++n)
        ao[orow + n * 16 + lc] = f2bf(accO[n][r] * inv[r]);
    }
  }

  // fused fixup: qt==5 blocks also write separator / pad rows for (seg, h)
  if (qt == 5) {
    if (seg < NSEG - 1) {
      if (tid < HDIM)
        ao[(size_t)(segbase + SEGLEN) * HID + h * HDIM + tid] =
            vT[(size_t)(h * HDIM + tid) * vstride + seg * VPAD + SEGLEN];
    } else {
      // zero rows 3047..3071 in this head's 64 columns (25 rows x 64 cols)
#pragma unroll
      for (int k = 0; k < 7; ++k) {
        const int idx = k * 256 + tid;
        if (idx < 25 * HDIM) {
          const int rr = idx >> 6, cc = idx & 63;
          ao[(size_t)(LTOT + rr) * HID + h * HDIM + cc] = 0;
        }
      }
    }
  }
}

extern "C" void kernel_launch(void* const* d_in, const int* in_sizes, int n_in,
                              void* d_out, int out_size, void* d_ws, size_t ws_size,
                              hipStream_t stream) {
  const float* x  = (const float*)d_in[0];
  const float* wq = (const float*)d_in[1];
  const float* bq = (const float*)d_in[2];
  const float* wk = (const float*)d_in[3];
  const float* bk = (const float*)d_in[4];
  const float* wv = (const float*)d_in[5];
  const float* bv = (const float*)d_in[6];
  const float* wo = (const float*)d_in[7];
  const float* bo = (const float*)d_in[8];
  float* out = (float*)d_out;

  u16* ws = (u16*)d_ws;
  u16* xblk = ws;                          // 3072*1024 (blocked)
  u16* wblk = xblk + (size_t)SEQ * HID;    // 3*1024*1024 (blocked)
  u16* wob  = wblk + (size_t)3 * HID * HID;  // 1024*1024 (linear)
  u16* qb   = wob + (size_t)HID * HID;
  u16* kbuf = qb  + (size_t)SEQ * HID;
  u16* vT   = kbuf + (size_t)SEQ * HID;    // [HID][NSEG*VPAD]
  u16* aob  = vT  + (size_t)HID * (NSEG * VPAD);

  cvt_all_kernel<<<3584, 256, 0, stream>>>(x, wq, wk, wv, wo, ws);

  qkv_gemm_kernel<<<dim3(SEQ / 128, 24), 512, 0, stream>>>(
      xblk, wblk, bq, bk, bv, qb, kbuf, vT);

  attn_kernel<<<768, 256, 0, stream>>>(qb, kbuf, vT, aob);

  out_gemm_kernel<<<dim3(SEQ / 128, HID / 64), 512, 0, stream>>>(aob, wob, bo, out);

  (void)in_sizes; (void)n_in; (void)out_size; (void)ws_size;
}

// Round 16
// 73.971 us; speedup vs baseline: 1.1383x; 1.0048x over previous
//
#include <hip/hip_runtime.h>

typedef unsigned short u16;
typedef __attribute__((ext_vector_type(8))) short short8;
typedef __attribute__((ext_vector_type(4))) float f32x4;

#define SEQ 3072
#define HID 1024
#define HEADS 16
#define HDIM 64
#define SEGLEN 380
#define SEGSTR 381
#define NSEG 8
#define LTOT 3047
#define VPAD 384  // padded per-segment stride in vT (16B-aligned bases)

static __device__ __forceinline__ u16 f2bf(float f) {
  unsigned u = __builtin_bit_cast(unsigned, f);
  u += 0x7fffu + ((u >> 16) & 1u);
  return (u16)(u >> 16);
}
static __device__ __forceinline__ float bf2f(u16 h) {
  unsigned u = ((unsigned)h) << 16;
  return __builtin_bit_cast(float, u);
}

static __device__ __forceinline__ void load_lds16(const void* g, void* l) {
  __builtin_amdgcn_global_load_lds((const __attribute__((address_space(1))) void*)g,
                                   (__attribute__((address_space(3))) void*)l, 16, 0, 0);
}

#define BAR() __builtin_amdgcn_s_barrier()
#define VM(N) asm volatile("s_waitcnt vmcnt(" #N ")" ::: "memory")

// ------- f32 -> bf16 conversion + tiling -------
// x -> xblk [24 Mtile][32 Ktile][128][32], chunk swizzle ^((row>>1)&3) baked in.
// wq|wk|wv -> wblk [24 Ctile][32 Ktile][128][32] same scheme.
// wo -> woblk [16 Ctile][16 Ktile][64][64], chunk swizzle ^(row&7) baked in.
__global__ void cvt_all_kernel(const float* __restrict__ x, const float* __restrict__ wq,
                               const float* __restrict__ wk, const float* __restrict__ wv,
                               const float* __restrict__ wo, u16* __restrict__ ws) {
  const int d = blockIdx.x * 256 + threadIdx.x;  // 16B-chunk index, total 917504
  const float* src;
  if (d < 393216) {  // x blocked
    const int tm = d >> 14, rem = d & 16383;
    const int tk = rem >> 9, rem2 = rem & 511;
    const int row = rem2 >> 2, cp = rem2 & 3;
    const int j = cp ^ ((row >> 1) & 3);
    src = x + ((size_t)(tm * 128 + row) * HID + tk * 32 + j * 8);
  } else if (d < 786432) {  // weights blocked
    const int dd = d - 393216;
    const int tc = dd >> 14, rem = dd & 16383;
    const int tk = rem >> 9, rem2 = rem & 511;
    const int row = rem2 >> 2, cp = rem2 & 3;
    const int j = cp ^ ((row >> 1) & 3);
    const int which = tc >> 3;
    const float* wsrc = (which == 0) ? wq : (which == 1) ? wk : wv;
    src = wsrc + ((size_t)((tc & 7) * 128 + row) * HID + tk * 32 + j * 8);
  } else {  // wo blocked [16 tc][16 tk][64][64]
    const int dd = d - 786432;
    const int tc = dd >> 13, rem = dd & 8191;
    const int tk = rem >> 9, rem2 = rem & 511;
    const int row = rem2 >> 3, cp = rem2 & 7;
    const int j = cp ^ (row & 7);
    src = wo + ((size_t)(tc * 64 + row) * HID + tk * 64 + j * 8);
  }
  float4 a = *reinterpret_cast<const float4*>(src);
  float4 b = *reinterpret_cast<const float4*>(src + 4);
  unsigned long long o0 = (unsigned long long)f2bf(a.x) |
                          ((unsigned long long)f2bf(a.y) << 16) |
                          ((unsigned long long)f2bf(a.z) << 32) |
                          ((unsigned long long)f2bf(a.w) << 48);
  unsigned long long o1 = (unsigned long long)f2bf(b.x) |
                          ((unsigned long long)f2bf(b.y) << 16) |
                          ((unsigned long long)f2bf(b.z) << 32) |
                          ((unsigned long long)f2bf(b.w) << 48);
  unsigned long long* dst = reinterpret_cast<unsigned long long*>(ws + (size_t)d * 8);
  dst[0] = o0;
  dst[1] = o1;
}

// ===== QKV GEMM: 128x128 tile, 512 thr (8 waves), BK=32, blocked operands =====
static __device__ __forceinline__ void stage_qkv(
    const u16* __restrict__ Ablk, const u16* __restrict__ Bblk,
    u16* As, u16* Bs, int t) {
  const int tid = threadIdx.x;
  const int w = tid >> 6;
  load_lds16(Ablk + (size_t)t * 4096 + tid * 8, As + (w * 64) * 8);
  load_lds16(Bblk + (size_t)t * 4096 + tid * 8, Bs + (w * 64) * 8);
}

static __device__ __forceinline__ void compute_qkv(
    const u16* As, const u16* Bs, int wr, int cb0, int lc, int lh, f32x4 (*acc)[2]) {
  short8 af[4], bfv[2];
#pragma unroll
  for (int m = 0; m < 4; ++m) {
    const int row = wr + m * 16 + lc;
    af[m] = *reinterpret_cast<const short8*>(As + row * 32 + (lh ^ ((row >> 1) & 3)) * 8);
  }
#pragma unroll
  for (int n = 0; n < 2; ++n) {
    const int row = cb0 + n * 32 + lc;
    bfv[n] = *reinterpret_cast<const short8*>(Bs + row * 32 + (lh ^ ((row >> 1) & 3)) * 8);
  }
  __builtin_amdgcn_s_setprio(1);
#pragma unroll
  for (int m = 0; m < 4; ++m)
#pragma unroll
    for (int n = 0; n < 2; ++n)
      acc[m][n] = __builtin_amdgcn_mfma_f32_16x16x32_bf16(af[m], bfv[n], acc[m][n], 0, 0, 0);
  __builtin_amdgcn_s_setprio(0);
}

// grid: (SEQ/128, 24); blockIdx.y: /8 -> {q,k,v}, &7 -> 128-col tile
__global__ __launch_bounds__(512) void qkv_gemm_kernel(
    const u16* __restrict__ xblk, const u16* __restrict__ wblk,
    const float* __restrict__ bq, const float* __restrict__ bk, const float* __restrict__ bv,
    u16* __restrict__ qb, u16* __restrict__ kbuf, u16* __restrict__ vT) {
  __shared__ u16 As[3][128 * 32];
  __shared__ u16 Bs[3][128 * 32];
  const int which = blockIdx.y >> 3;
  const float* bias = (which == 0) ? bq : (which == 1) ? bk : bv;
  const int rowBase = blockIdx.x * 128;
  const int colBase = (blockIdx.y & 7) * 128;
  const u16* Ablk = xblk + (size_t)blockIdx.x * 131072;
  const u16* Bblk = wblk + (size_t)blockIdx.y * 131072;
  const int tid = threadIdx.x;
  const int w = tid >> 6, l = tid & 63, lc = l & 15, lh = l >> 4;
  const int wr = (w >> 2) * 64;
  const int c2 = w & 3;
  const int cb0 = (c2 >> 1) * 64 + (c2 & 1) * 16;

  f32x4 acc[4][2];
  f32x4 z4 = {0.f, 0.f, 0.f, 0.f};
#pragma unroll
  for (int m = 0; m < 4; ++m) { acc[m][0] = z4; acc[m][1] = z4; }

  stage_qkv(Ablk, Bblk, As[0], Bs[0], 0);
  stage_qkv(Ablk, Bblk, As[1], Bs[1], 1);
#pragma unroll 1
  for (int t = 0; t < 30; t += 3) {
    stage_qkv(Ablk, Bblk, As[2], Bs[2], t + 2);
    VM(4); BAR();
    compute_qkv(As[0], Bs[0], wr, cb0, lc, lh, acc);
    BAR();
    stage_qkv(Ablk, Bblk, As[0], Bs[0], t + 3);
    VM(4); BAR();
    compute_qkv(As[1], Bs[1], wr, cb0, lc, lh, acc);
    BAR();
    stage_qkv(Ablk, Bblk, As[1], Bs[1], t + 4);
    VM(4); BAR();
    compute_qkv(As[2], Bs[2], wr, cb0, lc, lh, acc);
    BAR();
  }
  VM(2); BAR();
  compute_qkv(As[0], Bs[0], wr, cb0, lc, lh, acc);  // tile 30
  BAR();
  VM(0); BAR();
  compute_qkv(As[1], Bs[1], wr, cb0, lc, lh, acc);  // tile 31

  // epilogue: thread holds cols (col0, col0+32) -> RoPE pair is local
  const int f = (c2 & 1) * 16 + lc;  // [0,32)
  const int col0 = colBase + (c2 >> 1) * 64 + f;
  if (which < 2) {
    u16* outp = which ? kbuf : qb;
    const float bv0 = bias[col0];
    const float bv1 = bias[col0 + 32];
    const float invf = exp2f(-(float)f * 0.10381025296523007f);  // 10^(-f/32)
#pragma unroll
    for (int m = 0; m < 4; ++m) {
      const int row0 = rowBase + wr + m * 16 + lh * 4;
#pragma unroll
      for (int r = 0; r < 4; ++r) {
        const int row = row0 + r;
        const int rr = row % SEGSTR;
        const float pos = (float)((rr < SEGLEN) ? rr : 0);
        float sn, cs;
        sincosf(pos * invf, &sn, &cs);
        const float t1 = acc[m][0][r] + bv0;
        const float t2 = acc[m][1][r] + bv1;
        const size_t base = (size_t)row * HID + col0;
        outp[base] = f2bf(t1 * cs - t2 * sn);
        outp[base + 32] = f2bf(t1 * sn + t2 * cs);
      }
    }
  } else {
#pragma unroll
    for (int n = 0; n < 2; ++n) {
      const int col = col0 + n * 32;
      const float bvl = bias[col];
#pragma unroll
      for (int m = 0; m < 4; ++m) {
        const int row0 = rowBase + wr + m * 16 + lh * 4;
#pragma unroll
        for (int r = 0; r < 4; ++r) {
          const float v = acc[m][n][r] + bvl;
          const int row = row0 + r;
          const int sg = row / SEGSTR;
          const int j = row - sg * SEGSTR;
          if (sg < NSEG)
            vT[(size_t)col * (NSEG * VPAD) + sg * VPAD + j] = f2bf(v);
        }
      }
    }
  }
}

// ===== OUT GEMM: 128x64 tile, 512 thr, BK=64, fully blocked operands =====
// A-tile = aoblk[(bx*16 + t)] (16KB contiguous); B-tile = woblk[(by*16 + t)] (8KB).
static __device__ __forceinline__ void stage_out(
    const u16* __restrict__ Ab, const u16* __restrict__ Bb,
    u16* As, u16* Bs, int t) {
  const int tid = threadIdx.x;
  const int w = tid >> 6;
#pragma unroll
  for (int c = 0; c < 2; ++c)
    load_lds16(Ab + (size_t)t * 8192 + (c * 512 + tid) * 8, As + (c * 512 + w * 64) * 8);
  load_lds16(Bb + (size_t)t * 4096 + tid * 8, Bs + (w * 64) * 8);
}

static __device__ __forceinline__ void compute_out(
    const u16* As, const u16* Bs, int wrO, int wcO, int lc, int lh, f32x4 (*acc)[2]) {
  short8 af[2][2], bfv[2][2];
#pragma unroll
  for (int m = 0; m < 2; ++m) {
    const int row = wrO + m * 16 + lc;
#pragma unroll
    for (int ks = 0; ks < 2; ++ks)
      af[m][ks] = *reinterpret_cast<const short8*>(
          As + row * 64 + (((ks * 4 + lh) ^ (row & 7))) * 8);
  }
#pragma unroll
  for (int n = 0; n < 2; ++n) {
    const int row = wcO + n * 16 + lc;
#pragma unroll
    for (int ks = 0; ks < 2; ++ks)
      bfv[n][ks] = *reinterpret_cast<const short8*>(
          Bs + row * 64 + (((ks * 4 + lh) ^ (row & 7))) * 8);
  }
  __builtin_amdgcn_s_setprio(1);
#pragma unroll
  for (int ks = 0; ks < 2; ++ks)
#pragma unroll
    for (int m = 0; m < 2; ++m)
#pragma unroll
      for (int n = 0; n < 2; ++n)
        acc[m][n] = __builtin_amdgcn_mfma_f32_16x16x32_bf16(af[m][ks], bfv[n][ks], acc[m][n], 0, 0, 0);
  __builtin_amdgcn_s_setprio(0);
}

// grid: (SEQ/128, HID/64), 512 threads
__global__ __launch_bounds__(512) void out_gemm_kernel(
    const u16* __restrict__ aoblk, const u16* __restrict__ woblk,
    const float* __restrict__ bo, float* __restrict__ out) {
  __shared__ u16 As[3][128 * 64];
  __shared__ u16 Bs[3][64 * 64];
  const int bx = blockIdx.x, by = blockIdx.y;
  const int rowBase = bx * 128;
  const int colBase = by * 64;
  const u16* Ab = aoblk + (size_t)bx * 16 * 8192;
  const u16* Bb = woblk + (size_t)by * 16 * 4096;
  const int tid = threadIdx.x;
  const int w = tid >> 6, l = tid & 63, lc = l & 15, lh = l >> 4;
  const int wrO = (w >> 1) * 32, wcO = (w & 1) * 32;
  f32x4 acc[2][2];
  f32x4 z4 = {0.f, 0.f, 0.f, 0.f};
#pragma unroll
  for (int m = 0; m < 2; ++m) { acc[m][0] = z4; acc[m][1] = z4; }

  stage_out(Ab, Bb, As[0], Bs[0], 0);
  stage_out(Ab, Bb, As[1], Bs[1], 1);
#pragma unroll 1
  for (int t = 0; t < 12; t += 3) {
    stage_out(Ab, Bb, As[2], Bs[2], t + 2);
    VM(6); BAR();
    compute_out(As[0], Bs[0], wrO, wcO, lc, lh, acc);
    BAR();
    stage_out(Ab, Bb, As[0], Bs[0], t + 3);
    VM(6); BAR();
    compute_out(As[1], Bs[1], wrO, wcO, lc, lh, acc);
    BAR();
    stage_out(Ab, Bb, As[1], Bs[1], t + 4);
    VM(6); BAR();
    compute_out(As[2], Bs[2], wrO, wcO, lc, lh, acc);
    BAR();
  }
  // computed 0..11, staged 0..13
  stage_out(Ab, Bb, As[2], Bs[2], 14);
  VM(6); BAR();
  compute_out(As[0], Bs[0], wrO, wcO, lc, lh, acc);  // 12
  BAR();
  stage_out(Ab, Bb, As[0], Bs[0], 15);
  VM(6); BAR();
  compute_out(As[1], Bs[1], wrO, wcO, lc, lh, acc);  // 13
  BAR();
  VM(3); BAR();
  compute_out(As[2], Bs[2], wrO, wcO, lc, lh, acc);  // 14
  BAR();
  VM(0); BAR();
  compute_out(As[0], Bs[0], wrO, wcO, lc, lh, acc);  // 15

#pragma unroll
  for (int n = 0; n < 2; ++n) {
    const int col = colBase + wcO + n * 16 + lc;
    const float bvl = bo[col];
#pragma unroll
    for (int m = 0; m < 2; ++m) {
      const int row0 = rowBase + wrO + m * 16 + lh * 4;
#pragma unroll
      for (int r = 0; r < 4; ++r)
        out[(size_t)(row0 + r) * HID + col] = acc[m][n][r] + bvl;
    }
  }
}

// ---------- block-diagonal flash attention (LDS-staged K/V, no-max softmax) -------
// Output written in BLOCKED pre-swizzled layout [24 tm][16 tk=head][128][64]
// (chunk ^(row&7)) so out_gemm staging is fully linear.
__global__ __launch_bounds__(256) void attn_kernel(
    const u16* __restrict__ qb, const u16* __restrict__ kb,
    const u16* __restrict__ vT, u16* __restrict__ ao) {
  __shared__ u16 Ks[3][32 * 64];
  __shared__ u16 Vs[3][64 * 32];
  __shared__ u16 P_lds[4][16 * 32];
  const int tid = threadIdx.x;
  const int w = tid >> 6, l = tid & 63, lc = l & 15, lh = l >> 4;
  const int W = (blockIdx.x & 7) * 96 + (blockIdx.x >> 3);
  const int qt = W % 6;
  const int seg = (W / 6) & 7;
  const int h = W / 48;
  const int segbase = seg * SEGSTR;
  const int rloc = qt * 64 + w * 16;

  const u16* qrow = qb + (size_t)(segbase + rloc + lc) * HID + h * HDIM + lh * 8;
  const short8 qf0 = *reinterpret_cast<const short8*>(qrow);
  const short8 qf1 = *reinterpret_cast<const short8*>(qrow + 32);

  const size_t vstride = (size_t)NSEG * VPAD;
  const u16* kseg = kb + (size_t)segbase * HID + h * HDIM;
  const u16* vseg = vT + (size_t)h * HDIM * vstride + seg * VPAD;

  const int krow = tid >> 3;
  const int kj = (tid & 7) ^ (krow & 7);
  const int vd = tid >> 2;
  const int vj = (tid & 3) ^ ((vd >> 2) & 3);

  f32x4 z4 = {0.f, 0.f, 0.f, 0.f};
  f32x4 accO[4] = {z4, z4, z4, z4};
  float psum[4] = {0.f, 0.f, 0.f, 0.f};

  u16* pl = &P_lds[w][0];
  int wo0[4], wo1[4];
#pragma unroll
  for (int r = 0; r < 4; ++r) {
    const int prow = lh * 4 + r;
    const int sw = (prow >> 1) & 3;
    wo0[r] = prow * 32 + ((lc >> 3) ^ sw) * 8 + (lc & 7);
    wo1[r] = prow * 32 + ((2 + (lc >> 3)) ^ sw) * 8 + (lc & 7);
  }
  const int prd_off = lc * 32 + (lh ^ ((lc >> 1) & 3)) * 8;

#define STAGE(B, T)                                                                 \
  load_lds16(kseg + (size_t)((T) * 32 + krow) * HID + kj * 8, &Ks[B][0] + w * 512); \
  load_lds16(vseg + (size_t)vd * vstride + (T) * 32 + vj * 8, &Vs[B][0] + w * 512);

#define STEP(B, MASKED)                                                               \
  {                                                                                   \
    const u16* KB = &Ks[B][0];                                                        \
    const u16* VB = &Vs[B][0];                                                        \
    const int ks0 = (lh ^ (lc & 7)) * 8;                                              \
    const int ks1 = ((lh + 4) ^ (lc & 7)) * 8;                                        \
    const short8 k00 = *reinterpret_cast<const short8*>(KB + lc * 64 + ks0);          \
    const short8 k01 = *reinterpret_cast<const short8*>(KB + lc * 64 + ks1);          \
    const short8 k10 = *reinterpret_cast<const short8*>(KB + (16 + lc) * 64 + ks0);   \
    const short8 k11 = *reinterpret_cast<const short8*>(KB + (16 + lc) * 64 + ks1);   \
    f32x4 s0 = z4, s1 = z4;                                                           \
    __builtin_amdgcn_s_setprio(1);                                                    \
    s0 = __builtin_amdgcn_mfma_f32_16x16x32_bf16(qf0, k00, s0, 0, 0, 0);              \
    s0 = __builtin_amdgcn_mfma_f32_16x16x32_bf16(qf1, k01, s0, 0, 0, 0);              \
    s1 = __builtin_amdgcn_mfma_f32_16x16x32_bf16(qf0, k10, s1, 0, 0, 0);              \
    s1 = __builtin_amdgcn_mfma_f32_16x16x32_bf16(qf1, k11, s1, 0, 0, 0);              \
    __builtin_amdgcn_s_setprio(0);                                                    \
    float p0[4], p1[4];                                                               \
    _Pragma("unroll") for (int r = 0; r < 4; ++r) {                                   \
      p0[r] = (!(MASKED) || lc < 28) ? __expf(s0[r] * 0.125f) : 0.f;                  \
      p1[r] = (!(MASKED) || lc < 12) ? __expf(s1[r] * 0.125f) : 0.f;                  \
      psum[r] += p0[r] + p1[r];                                                       \
    }                                                                                 \
    _Pragma("unroll") for (int r = 0; r < 4; ++r) {                                   \
      pl[wo0[r]] = f2bf(p0[r]);                                                       \
      pl[wo1[r]] = f2bf(p1[r]);                                                       \
    }                                                                                 \
    const short8 pf = *reinterpret_cast<const short8*>(pl + prd_off);                 \
    const int vsw = (lh ^ (lc >> 2)) * 8;                                             \
    const short8 v0 = *reinterpret_cast<const short8*>(VB + lc * 32 + vsw);           \
    const short8 v1 = *reinterpret_cast<const short8*>(VB + (16 + lc) * 32 + vsw);    \
    const short8 v2 = *reinterpret_cast<const short8*>(VB + (32 + lc) * 32 + vsw);    \
    const short8 v3 = *reinterpret_cast<const short8*>(VB + (48 + lc) * 32 + vsw);    \
    __builtin_amdgcn_s_setprio(1);                                                    \
    accO[0] = __builtin_amdgcn_mfma_f32_16x16x32_bf16(pf, v0, accO[0], 0, 0, 0);      \
    accO[1] = __builtin_amdgcn_mfma_f32_16x16x32_bf16(pf, v1, accO[1], 0, 0, 0);      \
    accO[2] = __builtin_amdgcn_mfma_f32_16x16x32_bf16(pf, v2, accO[2], 0, 0, 0);      \
    accO[3] = __builtin_amdgcn_mfma_f32_16x16x32_bf16(pf, v3, accO[3], 0, 0, 0);      \
    __builtin_amdgcn_s_setprio(0);                                                    \
  }

  STAGE(0, 0);
  STAGE(1, 1);
#pragma unroll 1
  for (int t = 0; t < 9; t += 3) {
    STAGE(2, t + 2);
    VM(4); BAR();
    STEP(0, false);
    BAR();
    STAGE(0, t + 3);
    VM(4); BAR();
    STEP(1, false);
    BAR();
    STAGE(1, t + 4);
    VM(4); BAR();
    STEP(2, false);
    BAR();
  }
  STAGE(2, 11);
  VM(4); BAR();
  STEP(0, false);  // step 9
  BAR();
  VM(2); BAR();
  STEP(1, false);  // step 10
  BAR();
  VM(0); BAR();
  STEP(2, true);   // step 11: k rows 352..383, mask k >= 380
#undef STEP
#undef STAGE

  float inv[4];
#pragma unroll
  for (int r = 0; r < 4; ++r) {
    float s = psum[r];
    s += __shfl_xor(s, 1);
    s += __shfl_xor(s, 2);
    s += __shfl_xor(s, 4);
    s += __shfl_xor(s, 8);
    inv[r] = 1.0f / s;
  }
  // blocked output write: tile = (R>>7)*16 + h, row r=R&127, chunk ^(r&7)
#pragma unroll
  for (int r = 0; r < 4; ++r) {
    const int lrow = rloc + lh * 4 + r;
    if (lrow < SEGLEN) {
      const int R = segbase + lrow;
      const size_t base = (size_t)((R >> 7) * 16 + h) * 8192 + (size_t)(R & 127) * 64;
      const int sw = R & 7;
#pragma unroll
      for (int n = 0; n < 4; ++n) {
        const int kk = n * 16 + lc;
        ao[base + (((kk >> 3) ^ sw) * 8) + (kk & 7)] = f2bf(accO[n][r] * inv[r]);
      }
    }
  }

  // fused fixup (blocked): qt==5 blocks write separator / pad rows for (seg, h)
  if (qt == 5) {
    if (seg < NSEG - 1) {
      if (tid < HDIM) {
        const int R = segbase + SEGLEN;
        const size_t base = (size_t)((R >> 7) * 16 + h) * 8192 + (size_t)(R & 127) * 64;
        ao[base + (((tid >> 3) ^ (R & 7)) * 8) + (tid & 7)] =
            vT[(size_t)(h * HDIM + tid) * vstride + seg * VPAD + SEGLEN];
      }
    } else {
#pragma unroll
      for (int k = 0; k < 7; ++k) {
        const int idx = k * 256 + tid;
        if (idx < 25 * HDIM) {
          const int rr = idx >> 6, cc = idx & 63;
          const int R = LTOT + rr;
          const size_t base = (size_t)((R >> 7) * 16 + h) * 8192 + (size_t)(R & 127) * 64;
          ao[base + (((cc >> 3) ^ (R & 7)) * 8) + (cc & 7)] = 0;
        }
      }
    }
  }
}

extern "C" void kernel_launch(void* const* d_in, const int* in_sizes, int n_in,
                              void* d_out, int out_size, void* d_ws, size_t ws_size,
                              hipStream_t stream) {
  const float* x  = (const float*)d_in[0];
  const float* wq = (const float*)d_in[1];
  const float* bq = (const float*)d_in[2];
  const float* wk = (const float*)d_in[3];
  const float* bk = (const float*)d_in[4];
  const float* wv = (const float*)d_in[5];
  const float* bv = (const float*)d_in[6];
  const float* wo = (const float*)d_in[7];
  const float* bo = (const float*)d_in[8];
  float* out = (float*)d_out;

  u16* ws = (u16*)d_ws;
  u16* xblk  = ws;                            // 3072*1024 (blocked)
  u16* wblk  = xblk + (size_t)SEQ * HID;      // 3*1024*1024 (blocked)
  u16* woblk = wblk + (size_t)3 * HID * HID;  // 1024*1024 (blocked)
  u16* qb    = woblk + (size_t)HID * HID;
  u16* kbuf  = qb  + (size_t)SEQ * HID;
  u16* vT    = kbuf + (size_t)SEQ * HID;      // [HID][NSEG*VPAD]
  u16* aoblk = vT  + (size_t)HID * (NSEG * VPAD);  // 3072*1024 (blocked)

  cvt_all_kernel<<<3584, 256, 0, stream>>>(x, wq, wk, wv, wo, ws);

  qkv_gemm_kernel<<<dim3(SEQ / 128, 24), 512, 0, stream>>>(
      xblk, wblk, bq, bk, bv, qb, kbuf, vT);

  attn_kernel<<<768, 256, 0, stream>>>(qb, kbuf, vT, aoblk);

  out_gemm_kernel<<<dim3(SEQ / 128, HID / 64), 512, 0, stream>>>(aoblk, woblk, bo, out);

  (void)in_sizes; (void)n_in; (void)out_size; (void)ws_size;
}

// Round 17
// 72.556 us; speedup vs baseline: 1.1605x; 1.0195x over previous
//
#include <hip/hip_runtime.h>

typedef unsigned short u16;
typedef __attribute__((ext_vector_type(8))) short short8;
typedef __attribute__((ext_vector_type(4))) float f32x4;

#define SEQ 3072
#define HID 1024
#define HEADS 16
#define HDIM 64
#define SEGLEN 380
#define SEGSTR 381
#define NSEG 8
#define LTOT 3047

static __device__ __forceinline__ u16 f2bf(float f) {
  unsigned u = __builtin_bit_cast(unsigned, f);
  u += 0x7fffu + ((u >> 16) & 1u);
  return (u16)(u >> 16);
}
static __device__ __forceinline__ float bf2f(u16 h) {
  unsigned u = ((unsigned)h) << 16;
  return __builtin_bit_cast(float, u);
}

static __device__ __forceinline__ void load_lds16(const void* g, void* l) {
  __builtin_amdgcn_global_load_lds((const __attribute__((address_space(1))) void*)g,
                                   (__attribute__((address_space(3))) void*)l, 16, 0, 0);
}

#define BAR() __builtin_amdgcn_s_barrier()
#define VM(N) asm volatile("s_waitcnt vmcnt(" #N ")" ::: "memory")

// ------- f32 -> bf16 conversion + tiling -------
// x -> xblk [24 Mt][32 Kt][128][32] swz ^((row>>1)&3); w -> wblk same;
// wo -> woblk [16 Ct][16 Kt][64][64] swz ^(row&7).
// Extra 192 blocks: zero never-written K/V tail slots (tile 11, rows 29-31).
__global__ void cvt_all_kernel(const float* __restrict__ x, const float* __restrict__ wq,
                               const float* __restrict__ wk, const float* __restrict__ wv,
                               const float* __restrict__ wo, u16* __restrict__ ws,
                               u16* __restrict__ kblk, u16* __restrict__ vblk) {
  if (blockIdx.x >= 3584) {
    const int i = (blockIdx.x - 3584) * 256 + threadIdx.x;  // < 49152
    if (i < 24576) {  // K tails: linear rows 29-31 of tile 11 per (h,seg)
      const int tile = i / 192, r = i % 192;
      kblk[(size_t)(tile * 12 + 11) * 2048 + 1856 + r] = 0;
    } else {
      const int ii = i - 24576;
      const int tile = ii / 192, j = ii % 192;
      const int d = j / 3, kk = 29 + j % 3;
      vblk[(size_t)(tile * 12 + 11) * 2048 + d * 32 +
           ((3 ^ ((d >> 2) & 3)) * 8) + (kk & 7)] = 0;
    }
    return;
  }
  const int d = blockIdx.x * 256 + threadIdx.x;  // 16B-chunk index, total 917504
  const float* src;
  if (d < 393216) {  // x blocked
    const int tm = d >> 14, rem = d & 16383;
    const int tk = rem >> 9, rem2 = rem & 511;
    const int row = rem2 >> 2, cp = rem2 & 3;
    const int j = cp ^ ((row >> 1) & 3);
    src = x + ((size_t)(tm * 128 + row) * HID + tk * 32 + j * 8);
  } else if (d < 786432) {  // weights blocked
    const int dd = d - 393216;
    const int tc = dd >> 14, rem = dd & 16383;
    const int tk = rem >> 9, rem2 = rem & 511;
    const int row = rem2 >> 2, cp = rem2 & 3;
    const int j = cp ^ ((row >> 1) & 3);
    const int which = tc >> 3;
    const float* wsrc = (which == 0) ? wq : (which == 1) ? wk : wv;
    src = wsrc + ((size_t)((tc & 7) * 128 + row) * HID + tk * 32 + j * 8);
  } else {  // wo blocked
    const int dd = d - 786432;
    const int tc = dd >> 13, rem = dd & 8191;
    const int tk = rem >> 9, rem2 = rem & 511;
    const int row = rem2 >> 3, cp = rem2 & 7;
    const int j = cp ^ (row & 7);
    src = wo + ((size_t)(tc * 64 + row) * HID + tk * 64 + j * 8);
  }
  float4 a = *reinterpret_cast<const float4*>(src);
  float4 b = *reinterpret_cast<const float4*>(src + 4);
  unsigned long long o0 = (unsigned long long)f2bf(a.x) |
                          ((unsigned long long)f2bf(a.y) << 16) |
                          ((unsigned long long)f2bf(a.z) << 32) |
                          ((unsigned long long)f2bf(a.w) << 48);
  unsigned long long o1 = (unsigned long long)f2bf(b.x) |
                          ((unsigned long long)f2bf(b.y) << 16) |
                          ((unsigned long long)f2bf(b.z) << 32) |
                          ((unsigned long long)f2bf(b.w) << 48);
  unsigned long long* dst = reinterpret_cast<unsigned long long*>(ws + (size_t)d * 8);
  dst[0] = o0;
  dst[1] = o1;
}

// ===== QKV GEMM: 128x128 tile, 512 thr (8 waves), BK=32, blocked operands =====
static __device__ __forceinline__ void stage_qkv(
    const u16* __restrict__ Ablk, const u16* __restrict__ Bblk,
    u16* As, u16* Bs, int t) {
  const int tid = threadIdx.x;
  const int w = tid >> 6;
  load_lds16(Ablk + (size_t)t * 4096 + tid * 8, As + (w * 64) * 8);
  load_lds16(Bblk + (size_t)t * 4096 + tid * 8, Bs + (w * 64) * 8);
}

static __device__ __forceinline__ void compute_qkv(
    const u16* As, const u16* Bs, int wr, int cb0, int lc, int lh, f32x4 (*acc)[2]) {
  short8 af[4], bfv[2];
#pragma unroll
  for (int m = 0; m < 4; ++m) {
    const int row = wr + m * 16 + lc;
    af[m] = *reinterpret_cast<const short8*>(As + row * 32 + (lh ^ ((row >> 1) & 3)) * 8);
  }
#pragma unroll
  for (int n = 0; n < 2; ++n) {
    const int row = cb0 + n * 32 + lc;
    bfv[n] = *reinterpret_cast<const short8*>(Bs + row * 32 + (lh ^ ((row >> 1) & 3)) * 8);
  }
  __builtin_amdgcn_s_setprio(1);
#pragma unroll
  for (int m = 0; m < 4; ++m)
#pragma unroll
    for (int n = 0; n < 2; ++n)
      acc[m][n] = __builtin_amdgcn_mfma_f32_16x16x32_bf16(af[m], bfv[n], acc[m][n], 0, 0, 0);
  __builtin_amdgcn_s_setprio(0);
}

// grid: (SEQ/128, 24); blockIdx.y: /8 -> {q,k,v}, &7 -> 128-col tile
// q -> row-major qb; k -> kblk [h][seg][12][32x64] swz ^(kr&7);
// v -> vblk [h][seg][12][64x32] swz ^((d>>2)&3)
__global__ __launch_bounds__(512) void qkv_gemm_kernel(
    const u16* __restrict__ xblk, const u16* __restrict__ wblk,
    const float* __restrict__ bq, const float* __restrict__ bk, const float* __restrict__ bv,
    u16* __restrict__ qb, u16* __restrict__ kblk, u16* __restrict__ vblk) {
  __shared__ u16 As[3][128 * 32];
  __shared__ u16 Bs[3][128 * 32];
  const int which = blockIdx.y >> 3;
  const float* bias = (which == 0) ? bq : (which == 1) ? bk : bv;
  const int rowBase = blockIdx.x * 128;
  const int colBase = (blockIdx.y & 7) * 128;
  const u16* Ablk = xblk + (size_t)blockIdx.x * 131072;
  const u16* Bblk = wblk + (size_t)blockIdx.y * 131072;
  const int tid = threadIdx.x;
  const int w = tid >> 6, l = tid & 63, lc = l & 15, lh = l >> 4;
  const int wr = (w >> 2) * 64;
  const int c2 = w & 3;
  const int cb0 = (c2 >> 1) * 64 + (c2 & 1) * 16;

  f32x4 acc[4][2];
  f32x4 z4 = {0.f, 0.f, 0.f, 0.f};
#pragma unroll
  for (int m = 0; m < 4; ++m) { acc[m][0] = z4; acc[m][1] = z4; }

  stage_qkv(Ablk, Bblk, As[0], Bs[0], 0);
  stage_qkv(Ablk, Bblk, As[1], Bs[1], 1);
#pragma unroll 1
  for (int t = 0; t < 30; t += 3) {
    stage_qkv(Ablk, Bblk, As[2], Bs[2], t + 2);
    VM(4); BAR();
    compute_qkv(As[0], Bs[0], wr, cb0, lc, lh, acc);
    BAR();
    stage_qkv(Ablk, Bblk, As[0], Bs[0], t + 3);
    VM(4); BAR();
    compute_qkv(As[1], Bs[1], wr, cb0, lc, lh, acc);
    BAR();
    stage_qkv(Ablk, Bblk, As[1], Bs[1], t + 4);
    VM(4); BAR();
    compute_qkv(As[2], Bs[2], wr, cb0, lc, lh, acc);
    BAR();
  }
  VM(2); BAR();
  compute_qkv(As[0], Bs[0], wr, cb0, lc, lh, acc);  // tile 30
  BAR();
  VM(0); BAR();
  compute_qkv(As[1], Bs[1], wr, cb0, lc, lh, acc);  // tile 31

  // epilogue: thread holds cols (col0, col0+32) -> RoPE pair is local
  const int f = (c2 & 1) * 16 + lc;  // [0,32)
  const int col0 = colBase + (c2 >> 1) * 64 + f;
  if (which < 2) {
    const float bv0 = bias[col0];
    const float bv1 = bias[col0 + 32];
    const float invf = exp2f(-(float)f * 0.10381025296523007f);  // 10^(-f/32)
    const int h = col0 >> 6;   // head (for k path)
#pragma unroll
    for (int m = 0; m < 4; ++m) {
      const int row0 = rowBase + wr + m * 16 + lh * 4;
#pragma unroll
      for (int r = 0; r < 4; ++r) {
        const int row = row0 + r;
        const int rr = row % SEGSTR;
        const float pos = (float)((rr < SEGLEN) ? rr : 0);
        float sn, cs;
        sincosf(pos * invf, &sn, &cs);
        const float t1 = acc[m][0][r] + bv0;
        const float t2 = acc[m][1][r] + bv1;
        const u16 e0 = f2bf(t1 * cs - t2 * sn);
        const u16 e1 = f2bf(t1 * sn + t2 * cs);
        if (which == 0) {
          const size_t base = (size_t)row * HID + col0;
          qb[base] = e0;
          qb[base + 32] = e1;
        } else {
          const int sg = row / SEGSTR;
          if (sg < NSEG) {
            const int jj = row - sg * SEGSTR;
            const int tt = jj >> 5, kr = jj & 31;
            const size_t tb = (size_t)((h * 8 + sg) * 12 + tt) * 2048 + kr * 64;
            kblk[tb + (((f >> 3) ^ (kr & 7)) * 8) + (f & 7)] = e0;
            kblk[tb + ((((f + 32) >> 3) ^ (kr & 7)) * 8) + (f & 7)] = e1;
          }
        }
      }
    }
  } else {
#pragma unroll
    for (int n = 0; n < 2; ++n) {
      const int col = col0 + n * 32;
      const float bvl = bias[col];
      const int h = col >> 6, dd = col & 63;
#pragma unroll
      for (int m = 0; m < 4; ++m) {
        const int row0 = rowBase + wr + m * 16 + lh * 4;
#pragma unroll
        for (int r = 0; r < 4; ++r) {
          const int row = row0 + r;
          const int sg = row / SEGSTR;
          if (sg < NSEG) {
            const int jj = row - sg * SEGSTR;
            const int tt = jj >> 5, kk = jj & 31;
            vblk[(size_t)((h * 8 + sg) * 12 + tt) * 2048 + dd * 32 +
                 (((kk >> 3) ^ ((dd >> 2) & 3)) * 8) + (kk & 7)] =
                f2bf(acc[m][n][r] + bvl);
          }
        }
      }
    }
  }
}

// ===== OUT GEMM: 128x64 tile, 512 thr, BK=64, fully blocked operands =====
static __device__ __forceinline__ void stage_out(
    const u16* __restrict__ Ab, const u16* __restrict__ Bb,
    u16* As, u16* Bs, int t) {
  const int tid = threadIdx.x;
  const int w = tid >> 6;
#pragma unroll
  for (int c = 0; c < 2; ++c)
    load_lds16(Ab + (size_t)t * 8192 + (c * 512 + tid) * 8, As + (c * 512 + w * 64) * 8);
  load_lds16(Bb + (size_t)t * 4096 + tid * 8, Bs + (w * 64) * 8);
}

static __device__ __forceinline__ void compute_out(
    const u16* As, const u16* Bs, int wrO, int wcO, int lc, int lh, f32x4 (*acc)[2]) {
  short8 af[2][2], bfv[2][2];
#pragma unroll
  for (int m = 0; m < 2; ++m) {
    const int row = wrO + m * 16 + lc;
#pragma unroll
    for (int ks = 0; ks < 2; ++ks)
      af[m][ks] = *reinterpret_cast<const short8*>(
          As + row * 64 + (((ks * 4 + lh) ^ (row & 7))) * 8);
  }
#pragma unroll
  for (int n = 0; n < 2; ++n) {
    const int row = wcO + n * 16 + lc;
#pragma unroll
    for (int ks = 0; ks < 2; ++ks)
      bfv[n][ks] = *reinterpret_cast<const short8*>(
          Bs + row * 64 + (((ks * 4 + lh) ^ (row & 7))) * 8);
  }
  __builtin_amdgcn_s_setprio(1);
#pragma unroll
  for (int ks = 0; ks < 2; ++ks)
#pragma unroll
    for (int m = 0; m < 2; ++m)
#pragma unroll
      for (int n = 0; n < 2; ++n)
        acc[m][n] = __builtin_amdgcn_mfma_f32_16x16x32_bf16(af[m][ks], bfv[n][ks], acc[m][n], 0, 0, 0);
  __builtin_amdgcn_s_setprio(0);
}

// grid: (SEQ/128, HID/64), 512 threads
__global__ __launch_bounds__(512) void out_gemm_kernel(
    const u16* __restrict__ aoblk, const u16* __restrict__ woblk,
    const float* __restrict__ bo, float* __restrict__ out) {
  __shared__ u16 As[3][128 * 64];
  __shared__ u16 Bs[3][64 * 64];
  const int bx = blockIdx.x, by = blockIdx.y;
  const int rowBase = bx * 128;
  const int colBase = by * 64;
  const u16* Ab = aoblk + (size_t)bx * 16 * 8192;
  const u16* Bb = woblk + (size_t)by * 16 * 4096;
  const int tid = threadIdx.x;
  const int w = tid >> 6, l = tid & 63, lc = l & 15, lh = l >> 4;
  const int wrO = (w >> 1) * 32, wcO = (w & 1) * 32;
  f32x4 acc[2][2];
  f32x4 z4 = {0.f, 0.f, 0.f, 0.f};
#pragma unroll
  for (int m = 0; m < 2; ++m) { acc[m][0] = z4; acc[m][1] = z4; }

  stage_out(Ab, Bb, As[0], Bs[0], 0);
  stage_out(Ab, Bb, As[1], Bs[1], 1);
#pragma unroll 1
  for (int t = 0; t < 12; t += 3) {
    stage_out(Ab, Bb, As[2], Bs[2], t + 2);
    VM(6); BAR();
    compute_out(As[0], Bs[0], wrO, wcO, lc, lh, acc);
    BAR();
    stage_out(Ab, Bb, As[0], Bs[0], t + 3);
    VM(6); BAR();
    compute_out(As[1], Bs[1], wrO, wcO, lc, lh, acc);
    BAR();
    stage_out(Ab, Bb, As[1], Bs[1], t + 4);
    VM(6); BAR();
    compute_out(As[2], Bs[2], wrO, wcO, lc, lh, acc);
    BAR();
  }
  stage_out(Ab, Bb, As[2], Bs[2], 14);
  VM(6); BAR();
  compute_out(As[0], Bs[0], wrO, wcO, lc, lh, acc);  // 12
  BAR();
  stage_out(Ab, Bb, As[0], Bs[0], 15);
  VM(6); BAR();
  compute_out(As[1], Bs[1], wrO, wcO, lc, lh, acc);  // 13
  BAR();
  VM(3); BAR();
  compute_out(As[2], Bs[2], wrO, wcO, lc, lh, acc);  // 14
  BAR();
  VM(0); BAR();
  compute_out(As[0], Bs[0], wrO, wcO, lc, lh, acc);  // 15

#pragma unroll
  for (int n = 0; n < 2; ++n) {
    const int col = colBase + wcO + n * 16 + lc;
    const float bvl = bo[col];
#pragma unroll
    for (int m = 0; m < 2; ++m) {
      const int row0 = rowBase + wrO + m * 16 + lh * 4;
#pragma unroll
      for (int r = 0; r < 4; ++r)
        out[(size_t)(row0 + r) * HID + col] = acc[m][n][r] + bvl;
    }
  }
}

// ---------- block-diagonal flash attention (blocked K/V, no-max softmax) -------
// K/V tiles are contiguous pre-swizzled 4KB blocks -> staging fully linear.
// Output written in blocked layout [24 tm][16 h][128][64] (^(row&7)).
__global__ __launch_bounds__(256) void attn_kernel(
    const u16* __restrict__ qb, const u16* __restrict__ kblk,
    const u16* __restrict__ vblk, u16* __restrict__ ao) {
  __shared__ u16 Ks[3][32 * 64];
  __shared__ u16 Vs[3][64 * 32];
  __shared__ u16 P_lds[4][16 * 32];
  const int tid = threadIdx.x;
  const int w = tid >> 6, l = tid & 63, lc = l & 15, lh = l >> 4;
  const int W = (blockIdx.x & 7) * 96 + (blockIdx.x >> 3);
  const int qt = W % 6;
  const int seg = (W / 6) & 7;
  const int h = W / 48;
  const int segbase = seg * SEGSTR;
  const int rloc = qt * 64 + w * 16;

  const u16* qrow = qb + (size_t)(segbase + rloc + lc) * HID + h * HDIM + lh * 8;
  const short8 qf0 = *reinterpret_cast<const short8*>(qrow);
  const short8 qf1 = *reinterpret_cast<const short8*>(qrow + 32);

  const u16* ktiles = kblk + (size_t)(h * 8 + seg) * 12 * 2048;
  const u16* vtiles = vblk + (size_t)(h * 8 + seg) * 12 * 2048;

  f32x4 z4 = {0.f, 0.f, 0.f, 0.f};
  f32x4 accO[4] = {z4, z4, z4, z4};
  float psum[4] = {0.f, 0.f, 0.f, 0.f};

  u16* pl = &P_lds[w][0];
  int wo0[4], wo1[4];
#pragma unroll
  for (int r = 0; r < 4; ++r) {
    const int prow = lh * 4 + r;
    const int sw = (prow >> 1) & 3;
    wo0[r] = prow * 32 + ((lc >> 3) ^ sw) * 8 + (lc & 7);
    wo1[r] = prow * 32 + ((2 + (lc >> 3)) ^ sw) * 8 + (lc & 7);
  }
  const int prd_off = lc * 32 + (lh ^ ((lc >> 1) & 3)) * 8;

#define STAGE(B, T)                                                     \
  load_lds16(ktiles + (size_t)(T) * 2048 + tid * 8, &Ks[B][0] + w * 512); \
  load_lds16(vtiles + (size_t)(T) * 2048 + tid * 8, &Vs[B][0] + w * 512);

#define STEP(B, MASKED)                                                               \
  {                                                                                   \
    const u16* KB = &Ks[B][0];                                                        \
    const u16* VB = &Vs[B][0];                                                        \
    const int ks0 = (lh ^ (lc & 7)) * 8;                                              \
    const int ks1 = ((lh + 4) ^ (lc & 7)) * 8;                                        \
    const short8 k00 = *reinterpret_cast<const short8*>(KB + lc * 64 + ks0);          \
    const short8 k01 = *reinterpret_cast<const short8*>(KB + lc * 64 + ks1);          \
    const short8 k10 = *reinterpret_cast<const short8*>(KB + (16 + lc) * 64 + ks0);   \
    const short8 k11 = *reinterpret_cast<const short8*>(KB + (16 + lc) * 64 + ks1);   \
    f32x4 s0 = z4, s1 = z4;                                                           \
    __builtin_amdgcn_s_setprio(1);                                                    \
    s0 = __builtin_amdgcn_mfma_f32_16x16x32_bf16(qf0, k00, s0, 0, 0, 0);              \
    s0 = __builtin_amdgcn_mfma_f32_16x16x32_bf16(qf1, k01, s0, 0, 0, 0);              \
    s1 = __builtin_amdgcn_mfma_f32_16x16x32_bf16(qf0, k10, s1, 0, 0, 0);              \
    s1 = __builtin_amdgcn_mfma_f32_16x16x32_bf16(qf1, k11, s1, 0, 0, 0);              \
    __builtin_amdgcn_s_setprio(0);                                                    \
    float p0[4], p1[4];                                                               \
    _Pragma("unroll") for (int r = 0; r < 4; ++r) {                                   \
      p0[r] = (!(MASKED) || lc < 28) ? __expf(s0[r] * 0.125f) : 0.f;                  \
      p1[r] = (!(MASKED) || lc < 12) ? __expf(s1[r] * 0.125f) : 0.f;                  \
      psum[r] += p0[r] + p1[r];                                                       \
    }                                                                                 \
    _Pragma("unroll") for (int r = 0; r < 4; ++r) {                                   \
      pl[wo0[r]] = f2bf(p0[r]);                                                       \
      pl[wo1[r]] = f2bf(p1[r]);                                                       \
    }                                                                                 \
    const short8 pf = *reinterpret_cast<const short8*>(pl + prd_off);                 \
    const int vsw = (lh ^ (lc >> 2)) * 8;                                             \
    const short8 v0 = *reinterpret_cast<const short8*>(VB + lc * 32 + vsw);           \
    const short8 v1 = *reinterpret_cast<const short8*>(VB + (16 + lc) * 32 + vsw);    \
    const short8 v2 = *reinterpret_cast<const short8*>(VB + (32 + lc) * 32 + vsw);    \
    const short8 v3 = *reinterpret_cast<const short8*>(VB + (48 + lc) * 32 + vsw);    \
    __builtin_amdgcn_s_setprio(1);                                                    \
    accO[0] = __builtin_amdgcn_mfma_f32_16x16x32_bf16(pf, v0, accO[0], 0, 0, 0);      \
    accO[1] = __builtin_amdgcn_mfma_f32_16x16x32_bf16(pf, v1, accO[1], 0, 0, 0);      \
    accO[2] = __builtin_amdgcn_mfma_f32_16x16x32_bf16(pf, v2, accO[2], 0, 0, 0);      \
    accO[3] = __builtin_amdgcn_mfma_f32_16x16x32_bf16(pf, v3, accO[3], 0, 0, 0);      \
    __builtin_amdgcn_s_setprio(0);                                                    \
  }

  STAGE(0, 0);
  STAGE(1, 1);
#pragma unroll 1
  for (int t = 0; t < 9; t += 3) {
    STAGE(2, t + 2);
    VM(4); BAR();
    STEP(0, false);
    BAR();
    STAGE(0, t + 3);
    VM(4); BAR();
    STEP(1, false);
    BAR();
    STAGE(1, t + 4);
    VM(4); BAR();
    STEP(2, false);
    BAR();
  }
  STAGE(2, 11);
  VM(4); BAR();
  STEP(0, false);  // step 9
  BAR();
  VM(2); BAR();
  STEP(1, false);  // step 10
  BAR();
  VM(0); BAR();
  STEP(2, true);   // step 11: k rows 352..383, mask k >= 380
#undef STEP
#undef STAGE

  float inv[4];
#pragma unroll
  for (int r = 0; r < 4; ++r) {
    float s = psum[r];
    s += __shfl_xor(s, 1);
    s += __shfl_xor(s, 2);
    s += __shfl_xor(s, 4);
    s += __shfl_xor(s, 8);
    inv[r] = 1.0f / s;
  }
  // blocked output write: tile = (R>>7)*16 + h, row r=R&127, chunk ^(r&7)
#pragma unroll
  for (int r = 0; r < 4; ++r) {
    const int lrow = rloc + lh * 4 + r;
    if (lrow < SEGLEN) {
      const int R = segbase + lrow;
      const size_t base = (size_t)((R >> 7) * 16 + h) * 8192 + (size_t)(R & 127) * 64;
      const int sw = R & 7;
#pragma unroll
      for (int n = 0; n < 4; ++n) {
        const int kk = n * 16 + lc;
        ao[base + (((kk >> 3) ^ sw) * 8) + (kk & 7)] = f2bf(accO[n][r] * inv[r]);
      }
    }
  }

  // fused fixup: qt==5 blocks write separator / pad rows for (seg, h)
  if (qt == 5) {
    if (seg < NSEG - 1) {
      if (tid < HDIM) {
        const int dd = tid;
        const u16 sval = vblk[(size_t)((h * 8 + seg) * 12 + 11) * 2048 + dd * 32 +
                              ((3 ^ ((dd >> 2) & 3)) * 8) + 4];  // kk=28 (j=380)
        const int R = segbase + SEGLEN;
        const size_t base = (size_t)((R >> 7) * 16 + h) * 8192 + (size_t)(R & 127) * 64;
        ao[base + (((dd >> 3) ^ (R & 7)) * 8) + (dd & 7)] = sval;
      }
    } else {
#pragma unroll
      for (int k = 0; k < 7; ++k) {
        const int idx = k * 256 + tid;
        if (idx < 25 * HDIM) {
          const int rr = idx >> 6, cc = idx & 63;
          const int R = LTOT + rr;
          const size_t base = (size_t)((R >> 7) * 16 + h) * 8192 + (size_t)(R & 127) * 64;
          ao[base + (((cc >> 3) ^ (R & 7)) * 8) + (cc & 7)] = 0;
        }
      }
    }
  }
}

extern "C" void kernel_launch(void* const* d_in, const int* in_sizes, int n_in,
                              void* d_out, int out_size, void* d_ws, size_t ws_size,
                              hipStream_t stream) {
  const float* x  = (const float*)d_in[0];
  const float* wq = (const float*)d_in[1];
  const float* bq = (const float*)d_in[2];
  const float* wk = (const float*)d_in[3];
  const float* bk = (const float*)d_in[4];
  const float* wv = (const float*)d_in[5];
  const float* bv = (const float*)d_in[6];
  const float* wo = (const float*)d_in[7];
  const float* bo = (const float*)d_in[8];
  float* out = (float*)d_out;

  u16* ws = (u16*)d_ws;
  u16* xblk  = ws;                            // 3072*1024 (blocked)
  u16* wblk  = xblk + (size_t)SEQ * HID;      // 3*1024*1024 (blocked)
  u16* woblk = wblk + (size_t)3 * HID * HID;  // 1024*1024 (blocked)
  u16* qb    = woblk + (size_t)HID * HID;     // 3072*1024 row-major
  u16* kblk  = qb   + (size_t)SEQ * HID;      // 16*8*12*2048
  u16* vblk  = kblk + (size_t)16 * 8 * 12 * 2048;
  u16* aoblk = vblk + (size_t)16 * 8 * 12 * 2048;  // 3072*1024 (blocked)

  cvt_all_kernel<<<3776, 256, 0, stream>>>(x, wq, wk, wv, wo, ws, kblk, vblk);

  qkv_gemm_kernel<<<dim3(SEQ / 128, 24), 512, 0, stream>>>(
      xblk, wblk, bq, bk, bv, qb, kblk, vblk);

  attn_kernel<<<768, 256, 0, stream>>>(qb, kblk, vblk, aoblk);

  out_gemm_kernel<<<dim3(SEQ / 128, HID / 64), 512, 0, stream>>>(aoblk, woblk, bo, out);

  (void)in_sizes; (void)n_in; (void)out_size; (void)ws_size;
}